// Round 12
// baseline (708.630 us; speedup 1.0000x reference)
//
#include <hip/hip_runtime.h>

// ===========================================================================
// ViewGCNEncoder r12. Proven dtype model: f32 in / f32 out / bf16-graded,
// masks sniffed. r11->r12: SpMM for L1/L2 becomes XCD-PINNED 32-col slices
// (slice = blockIdx%8 -> one 3.2MB slice per XCD's 4MB L2; r11 counters
// showed 50% of gathers missing L2 at 3.4 TB/s on the cross-XCD path).
// 4 rows per gather instr (lane quarters), shfl_xor reduction. L3 SpMM,
// GEMM, CSR, conversions frozen from r11. Workspace ~84 MB.
// ===========================================================================

typedef unsigned short ushort_t;
typedef __attribute__((ext_vector_type(8))) short bf16x8;   // 8 bf16 = 4 VGPRs
typedef __attribute__((ext_vector_type(4))) float f32x4;
typedef __attribute__((ext_vector_type(2))) unsigned int u32x2;

__device__ __forceinline__ float bf2f(ushort_t u) {
  return __uint_as_float(((unsigned int)u) << 16);
}
__device__ __forceinline__ ushort_t f2bf(float f) {
  unsigned int u = __float_as_uint(f);
  return (ushort_t)((u + 0x7FFFu + ((u >> 16) & 1u)) >> 16);  // RNE
}
__device__ __forceinline__ float read_f(const void* p, int fm, size_t i) {
  return fm ? bf2f(((const ushort_t*)p)[i]) : ((const float*)p)[i];
}

// ---------------- fused dtype sniff (frozen) ----------------
__global__ void sniff_all_kernel(const void* __restrict__ x,
                                 const void* __restrict__ m1,
                                 const void* __restrict__ m2,
                                 int* __restrict__ modes) {
  if (blockIdx.x == 0) {
    __shared__ int bfok;
    if (threadIdx.x == 0) bfok = 1;
    __syncthreads();
    for (int i = threadIdx.x; i < 8192; i += blockDim.x) {
      ushort_t h = ((const ushort_t*)x)[i];
      int e = (h >> 7) & 0xFF;
      if (!(h == 0 || (e >= 95 && e <= 133))) atomicAnd(&bfok, 0);
    }
    __syncthreads();
    if (threadIdx.x == 0) modes[0] = bfok;   // 1=bf16, 0=f32
  } else {
    const void* p = (blockIdx.x == 1) ? m1 : m2;
    __shared__ int ok[4];  // [i32, f32, bf16, u8]
    if (threadIdx.x < 4) ok[threadIdx.x] = 1;
    __syncthreads();
    for (int i = threadIdx.x; i < 4096; i += blockDim.x) {
      unsigned int w = ((const unsigned int*)p)[i];
      if (!(w == 0u || w == 1u)) atomicAnd(&ok[0], 0);
      if (!(w == 0u || w == 0x3F800000u)) atomicAnd(&ok[1], 0);
      unsigned int h16 = w >> 16, l16 = w & 0xFFFFu;
      if (!((h16 == 0u || h16 == 0x3F80u) && (l16 == 0u || l16 == 0x3F80u)))
        atomicAnd(&ok[2], 0);
      if (((w | (w >> 8) | (w >> 16) | (w >> 24)) & 0xFEu) != 0u) atomicAnd(&ok[3], 0);
    }
    __syncthreads();
    if (threadIdx.x == 0)
      modes[blockIdx.x] = ok[0] ? 1 : (ok[1] ? 2 : (ok[2] ? 3 : 0));
  }
}

__device__ __forceinline__ bool mask_keep(const void* mask, int mm, size_t o) {
  switch (mm) {
    case 1:  return ((const int*)mask)[o] != 0;
    case 2:  return ((const unsigned int*)mask)[o] != 0u;
    case 3:  return ((const ushort_t*)mask)[o] != 0;
    default: return ((const unsigned char*)mask)[o] != 0;
  }
}

// ---------------- CSR build (frozen) ----------------
__global__ void hist_kernel(const int* __restrict__ rows, int* __restrict__ cnt, int E) {
  int i = blockIdx.x * blockDim.x + threadIdx.x;
  int stride = gridDim.x * blockDim.x;
  for (; i < E; i += stride) atomicAdd(&cnt[rows[i]], 1);
}

__global__ void scan_part_kernel(const int* __restrict__ cnt, int* __restrict__ part, int n) {
  __shared__ int s[256];
  int i = blockIdx.x * 256 + threadIdx.x;
  s[threadIdx.x] = (i < n) ? cnt[i] : 0;
  __syncthreads();
  for (int off = 128; off > 0; off >>= 1) {
    if (threadIdx.x < off) s[threadIdx.x] += s[threadIdx.x + off];
    __syncthreads();
  }
  if (threadIdx.x == 0) part[blockIdx.x] = s[0];
}

__global__ __launch_bounds__(1024) void scan_top_kernel(int* __restrict__ part, int P) {
  __shared__ int s[1024];
  int t = threadIdx.x;
  int v = (t < P) ? part[t] : 0;
  s[t] = v;
  __syncthreads();
  for (int off = 1; off < 1024; off <<= 1) {
    int x = s[t];
    int y = (t >= off) ? s[t - off] : 0;
    __syncthreads();
    s[t] = x + y;
    __syncthreads();
  }
  if (t < P) part[t] = s[t] - v;   // exclusive
}

__global__ void scan_apply_kernel(const int* __restrict__ cnt, const int* __restrict__ part,
                                  int* __restrict__ row_start, int n) {
  __shared__ int s[256];
  int base = part[blockIdx.x];
  int i = blockIdx.x * 256 + threadIdx.x;
  int v = (i < n) ? cnt[i] : 0;
  s[threadIdx.x] = v;
  __syncthreads();
  for (int off = 1; off < 256; off <<= 1) {
    int x = s[threadIdx.x];
    int y = (threadIdx.x >= off) ? s[threadIdx.x - off] : 0;
    __syncthreads();
    s[threadIdx.x] = x + y;
    __syncthreads();
  }
  if (i < n) row_start[i] = base + s[threadIdx.x] - v;
  if (i == n - 1) row_start[n] = base + s[threadIdx.x];
}

__global__ void scatter_kernel(const int* __restrict__ rows, const int* __restrict__ cols,
                               const void* __restrict__ vals, const int* __restrict__ fm_p,
                               const int* __restrict__ row_start, int* __restrict__ fill,
                               int2* __restrict__ ecv, int E) {
  int fm = *fm_p;
  int i = blockIdx.x * blockDim.x + threadIdx.x;
  int stride = gridDim.x * blockDim.x;
  for (; i < E; i += stride) {
    int r = rows[i];
    int pos = atomicAdd(&fill[r], 1);
    int idx = row_start[r] + pos;
    ecv[idx] = make_int2(cols[i], __float_as_int(read_f(vals, fm, i)));
  }
}

// ---------------- fused conversions (frozen) ----------------
__global__ void split_w_all_kernel(const void* __restrict__ W1, const void* __restrict__ W2,
                                   const void* __restrict__ W3, const int* __restrict__ fm_p,
                                   ushort_t* __restrict__ whi, ushort_t* __restrict__ wlo,
                                   int n1, int n2, int n3) {
  int fm = *fm_p;
  int total = n1 + n2 + n3;
  int i = blockIdx.x * blockDim.x + threadIdx.x;
  int stride = gridDim.x * blockDim.x;
  for (; i < total; i += stride) {
    const void* src; int j;
    if (i < n1) { src = W1; j = i; }
    else if (i < n1 + n2) { src = W2; j = i - n1; }
    else { src = W3; j = i - n1 - n2; }
    float v = read_f(src, fm, j);
    ushort_t h = f2bf(v);
    whi[i] = h;
    wlo[i] = f2bf(v - bf2f(h));
  }
}

__global__ void cvt_bias_all_kernel(const void* __restrict__ b1, const void* __restrict__ b2,
                                    const void* __restrict__ b3, const int* __restrict__ fm_p,
                                    float* __restrict__ dst, int n1, int n2, int n3) {
  int fm = *fm_p;
  int i = threadIdx.x + blockIdx.x * blockDim.x;
  int total = n1 + n2 + n3;
  if (i >= total) return;
  const void* src; int j;
  if (i < n1) { src = b1; j = i; }
  else if (i < n1 + n2) { src = b2; j = i - n1; }
  else { src = b3; j = i - n1 - n2; }
  dst[i] = read_f(src, fm, j);
}

__global__ void cvt_bf16x4_kernel(const void* __restrict__ src, const int* __restrict__ fm_p,
                                  ushort_t* __restrict__ dst, int n4) {
  int fm = *fm_p;
  int i = blockIdx.x * blockDim.x + threadIdx.x;
  int stride = gridDim.x * blockDim.x;
  for (; i < n4; i += stride) {
    if (fm == 0) {
      f32x4 v = ((const f32x4*)src)[i];
      unsigned int lo = (unsigned int)f2bf(v[0]) | ((unsigned int)f2bf(v[1]) << 16);
      unsigned int hi = (unsigned int)f2bf(v[2]) | ((unsigned int)f2bf(v[3]) << 16);
      ((u32x2*)dst)[i] = (u32x2){lo, hi};
    } else {
      ((u32x2*)dst)[i] = ((const u32x2*)src)[i];
    }
  }
}

// ---------------- GEMM: W-in-registers + A-prefetch (frozen) ----------------
template<int KC>
__global__ __launch_bounds__(256) void gemm_breg_kernel(
    const ushort_t* __restrict__ A,
    const ushort_t* __restrict__ Whi, const ushort_t* __restrict__ Wlo,
    const float* __restrict__ bias, ushort_t* __restrict__ g, int ldg,
    int M, int nct) {
  const int K = KC * 32;
  int wave = threadIdx.x >> 6, lane = threadIdx.x & 63;
  int gw = blockIdx.x * 4 + wave;
  int NW = gridDim.x * 4;
  int mr = lane & 15, quad = lane >> 4;
  int ct = gw % nct;
  int nrt = (M + 15) >> 4;
  int ntasks = nct * nrt;
  if (gw >= ntasks) return;

  bf16x8 wh[KC], wl[KC];
  {
    const ushort_t* wp = Whi + (size_t)(ct * 16 + mr) * K + quad * 8;
    const ushort_t* wq = Wlo + (size_t)(ct * 16 + mr) * K + quad * 8;
#pragma unroll
    for (int kc = 0; kc < KC; ++kc) {
      wh[kc] = *(const bf16x8*)(wp + kc * 32);
      wl[kc] = *(const bf16x8*)(wq + kc * 32);
    }
  }
  int col = ct * 16 + mr;
  float bv = bias[col];

  int task = gw;
  bf16x8 af[KC];
  {
    int m = (task / nct) * 16 + mr; if (m >= M) m = M - 1;
    const ushort_t* ap = A + (size_t)m * K + quad * 8;
#pragma unroll
    for (int kc = 0; kc < KC; ++kc) af[kc] = *(const bf16x8*)(ap + kc * 32);
  }

#pragma unroll 1
  for (;;) {
    int next = task + NW;
    bool has_next = next < ntasks;
    bf16x8 afn[KC];
    if (has_next) {
      int m = (next / nct) * 16 + mr; if (m >= M) m = M - 1;
      const ushort_t* ap = A + (size_t)m * K + quad * 8;
#pragma unroll
      for (int kc = 0; kc < KC; ++kc) afn[kc] = *(const bf16x8*)(ap + kc * 32);
    }

    f32x4 acc[4];
#pragma unroll
    for (int t = 0; t < 4; ++t) acc[t] = (f32x4){0.f, 0.f, 0.f, 0.f};
#pragma unroll
    for (int kc = 0; kc < KC; ++kc) {
      acc[(2 * kc) & 3] = __builtin_amdgcn_mfma_f32_16x16x32_bf16(af[kc], wh[kc], acc[(2 * kc) & 3], 0, 0, 0);
      acc[(2 * kc + 1) & 3] = __builtin_amdgcn_mfma_f32_16x16x32_bf16(af[kc], wl[kc], acc[(2 * kc + 1) & 3], 0, 0, 0);
    }
    int m0 = (task / nct) * 16;
#pragma unroll
    for (int r = 0; r < 4; ++r) {
      int row = m0 + quad * 4 + r;
      float s = ((acc[0][r] + acc[1][r]) + (acc[2][r] + acc[3][r])) + bv;
      if (row < M) g[(size_t)row * ldg + col] = f2bf(s);
    }
    if (!has_next) break;
#pragma unroll
    for (int kc = 0; kc < KC; ++kc) af[kc] = afn[kc];
    task = next;
  }
}

// ---------------- SpMM v8: XCD-pinned 32-col slices -------------------------
// out[r, slice*32 + c] = sum_e val[e]*G[col[e], slice*32 + c]   (act+mask).
// NS slices of 32 cols; slice = (blockIdx%8)/(8/NS) -> each XCD's L2 caches
// one 3.2MB slice (round-robin blockIdx->XCD). Lane quarters q=0..3 each own
// an edge -> one gather instr covers 4 rows x 64B; shfl_xor(16,32) reduction.
// 8-edge batches (full + clamped tail, r11 waste profile).
template<int NS>
__global__ __launch_bounds__(256) void spmm8_kernel(
    const int* __restrict__ row_start, const int2* __restrict__ ecv,
    const ushort_t* __restrict__ G, int D,
    const void* __restrict__ mask, const int* __restrict__ mmode_p,
    ushort_t* __restrict__ outp, int N) {
  const int SPAN = 8 / NS;                 // block-lanes sharing a slice
  int b8 = blockIdx.x & 7;
  int grp = blockIdx.x >> 3;
  int slice = b8 / SPAN;
  int sub = b8 - slice * SPAN;
  int wave = threadIdx.x >> 6, lane = threadIdx.x & 63;
  int r = grp * (4 * SPAN) + sub * 4 + wave;
  if (r >= N) return;
  int q = lane >> 4;                       // quarter: which edge of 4
  int cp = lane & 15;                      // col pair within slice
  int c0 = slice * 32 + cp * 2;
  int e  = __builtin_amdgcn_readfirstlane(row_start[r]);
  int e1 = __builtin_amdgcn_readfirstlane(row_start[r + 1]);
  float a0 = 0.f, a1 = 0.f;

  // full 8-edge batches: 2 gather instrs, each 4 rows x 64B
  for (; e + 8 <= e1; e += 8) {
    int2 cvA = ecv[e + q];
    int2 cvB = ecv[e + 4 + q];
    unsigned int gA = *(const unsigned int*)(G + (size_t)cvA.x * D + c0);
    unsigned int gB = *(const unsigned int*)(G + (size_t)cvB.x * D + c0);
    float vA = __int_as_float(cvA.y), vB = __int_as_float(cvB.y);
    a0 += vA * bf2f((ushort_t)gA);
    a1 += vA * bf2f((ushort_t)(gA >> 16));
    a0 += vB * bf2f((ushort_t)gB);
    a1 += vB * bf2f((ushort_t)(gB >> 16));
  }
  // clamped tail batch
  if (e < e1) {
    int eA = e + q, eB = e + 4 + q;
    bool okA = eA < e1, okB = eB < e1;
    int2 cvA = ecv[okA ? eA : e1 - 1];
    int2 cvB = ecv[okB ? eB : e1 - 1];
    unsigned int gA = *(const unsigned int*)(G + (size_t)cvA.x * D + c0);
    unsigned int gB = *(const unsigned int*)(G + (size_t)cvB.x * D + c0);
    float vA = okA ? __int_as_float(cvA.y) : 0.f;
    float vB = okB ? __int_as_float(cvB.y) : 0.f;
    a0 += vA * bf2f((ushort_t)gA);
    a1 += vA * bf2f((ushort_t)(gA >> 16));
    a0 += vB * bf2f((ushort_t)gB);
    a1 += vB * bf2f((ushort_t)(gB >> 16));
  }

  // reduce across quarters (xor 16 then 32 -> all lanes hold full sums)
  a0 += __shfl_xor(a0, 16);
  a0 += __shfl_xor(a0, 32);
  a1 += __shfl_xor(a1, 16);
  a1 += __shfl_xor(a1, 32);

  if (lane < 16) {
    size_t o = (size_t)r * D + c0;
    int mm = *mmode_p;
    float t0 = (a0 >= 0.f) ? a0 : 0.2f * a0;             // leaky relu 0.2
    float t1 = (a1 >= 0.f) ? a1 : 0.2f * a1;
    t0 = mask_keep(mask, mm, o) ? t0 * 1.25f : 0.f;      // keep = 1/(1-0.2)
    t1 = mask_keep(mask, mm, o + 1) ? t1 * 1.25f : 0.f;
    unsigned int pk = (unsigned int)f2bf(t0) | ((unsigned int)f2bf(t1) << 16);
    *(unsigned int*)(outp + o) = pk;
  }
}

// ---------------- SpMM v7 (frozen, used for L3) ------------------------------
template<int MODE, int VEC>
__global__ __launch_bounds__(256) void spmm7_kernel(
    const int* __restrict__ row_start, const int2* __restrict__ ecv,
    const ushort_t* __restrict__ G, int D,
    const void* __restrict__ mask, const int* __restrict__ mmode_p,
    void* __restrict__ outp, int N) {
  int wave = threadIdx.x >> 6, lane = threadIdx.x & 63;
  int r = blockIdx.x * 4 + wave;
  if (r >= N) return;
  int f0 = lane * VEC;
  int e  = __builtin_amdgcn_readfirstlane(row_start[r]);
  int e1 = __builtin_amdgcn_readfirstlane(row_start[r + 1]);
  float a[VEC];
#pragma unroll
  for (int q = 0; q < VEC; ++q) a[q] = 0.f;

  for (; e + 8 <= e1; e += 8) {
    int2 cv[8];
#pragma unroll
    for (int j = 0; j < 8; ++j) cv[j] = ecv[e + j];
    ushort_t h[8];
#pragma unroll
    for (int j = 0; j < 8; ++j) h[j] = G[(size_t)cv[j].x * D + f0];
#pragma unroll
    for (int j = 0; j < 8; ++j) a[0] += __int_as_float(cv[j].y) * bf2f(h[j]);
  }
  if (e < e1) {
    int idx[8]; float v[8];
#pragma unroll
    for (int j = 0; j < 8; ++j) {
      int ee = e + j;
      bool ok = ee < e1;
      int2 cv = ecv[ok ? ee : e1 - 1];
      idx[j] = cv.x;
      v[j] = ok ? __int_as_float(cv.y) : 0.f;
    }
    ushort_t h[8];
#pragma unroll
    for (int j = 0; j < 8; ++j) h[j] = G[(size_t)idx[j] * D + f0];
#pragma unroll
    for (int j = 0; j < 8; ++j) a[0] += v[j] * bf2f(h[j]);
  }

  size_t o = (size_t)r * D + f0;
  ((float*)outp)[o] = a[0];   // MODE 0 path (final f32 out)
}

// ---------------- launch ----------------
extern "C" void kernel_launch(void* const* d_in, const int* in_sizes, int n_in,
                              void* d_out, int out_size, void* d_ws, size_t ws_size,
                              hipStream_t stream) {
  const void* x     = d_in[0];
  const int*  rows  = (const int*)d_in[1];
  const int*  cols  = (const int*)d_in[2];
  const void* vals  = d_in[3];
  const void* W1    = d_in[4];
  const void* b1    = d_in[5];
  const void* W2    = d_in[6];
  const void* b2    = d_in[7];
  const void* W3    = d_in[8];
  const void* b3    = d_in[9];
  const void* mask1 = d_in[10];
  const void* mask2 = d_in[11];

  const int H1  = in_sizes[5];            // 256
  const int H2  = in_sizes[7];            // 128
  const int OUT = in_sizes[9];            // 64
  const int IN  = in_sizes[4] / H1;       // 256
  const int N   = in_sizes[0] / IN;       // 50000
  const int E   = in_sizes[1];            // 800000
  const int W1n = in_sizes[4], W2n = in_sizes[6], W3n = in_sizes[8];

  char* ws = (char*)d_ws;
  size_t off = 0;
  auto alloc = [&](size_t bytes) -> void* {
    void* p = ws + off;
    off = (off + bytes + 255) & ~(size_t)255;
    return p;
  };
  int*      modes     = (int*)alloc(4 * 4);
  int*      row_start = (int*)alloc((size_t)(N + 1) * 4);
  int*      cnt       = (int*)alloc((size_t)N * 4);
  int*      part      = (int*)alloc(1024 * 4);
  int2*     ecv       = (int2*)alloc((size_t)E * 8);
  ushort_t* whi       = (ushort_t*)alloc((size_t)(W1n + W2n + W3n) * 2);
  ushort_t* wlo       = (ushort_t*)alloc((size_t)(W1n + W2n + W3n) * 2);
  float*    biasf     = (float*)alloc((size_t)(H1 + H2 + OUT) * 4);
  ushort_t* bufA      = (ushort_t*)alloc((size_t)N * H1 * 2);   // 25.6 MB
  ushort_t* bufB      = (ushort_t*)alloc((size_t)N * H1 * 2);   // 25.6 MB
  ushort_t* bufC      = (ushort_t*)alloc((size_t)N * H1 * 2);   // 25.6 MB
  // total ~84 MB (<=110 MB proven safe in r3)

  int* fmode = modes;
  int* mm1   = modes + 1;
  int* mm2   = modes + 2;
  ushort_t* w1hi = whi,             *w1lo = wlo;
  ushort_t* w2hi = whi + W1n,       *w2lo = wlo + W1n;
  ushort_t* w3hi = whi + W1n + W2n, *w3lo = wlo + W1n + W2n;

  sniff_all_kernel<<<3, 256, 0, stream>>>(x, mask1, mask2, modes);

  // CSR build with parallel scan
  const int P = (N + 255) / 256;
  hipMemsetAsync(cnt, 0, (size_t)N * 4, stream);
  hist_kernel<<<1024, 256, 0, stream>>>(rows, cnt, E);
  scan_part_kernel<<<P, 256, 0, stream>>>(cnt, part, N);
  scan_top_kernel<<<1, 1024, 0, stream>>>(part, P);
  scan_apply_kernel<<<P, 256, 0, stream>>>(cnt, part, row_start, N);
  hipMemsetAsync(cnt, 0, (size_t)N * 4, stream);
  scatter_kernel<<<1024, 256, 0, stream>>>(rows, cols, vals, fmode, row_start, cnt, ecv, E);

  // conversions (fused)
  int wtot = W1n + W2n + W3n;
  split_w_all_kernel<<<(wtot + 255) / 256, 256, 0, stream>>>(
      W1, W2, W3, fmode, whi, wlo, W1n, W2n, W3n);
  cvt_bias_all_kernel<<<(H1 + H2 + OUT + 255) / 256, 256, 0, stream>>>(
      b1, b2, b3, fmode, biasf, H1, H2, OUT);
  cvt_bf16x4_kernel<<<2048, 256, 0, stream>>>(x, fmode, bufA, (N * IN) / 4);

  const int GEMM_BLOCKS = 2048;            // 8192 waves; % {16,8,4} == 0

  // layer 1: GEMM(IN->H1) -> SpMM v8 (D=256, 8 slices, act+mask1)
  gemm_breg_kernel<8><<<GEMM_BLOCKS, 256, 0, stream>>>(
      bufA, w1hi, w1lo, biasf, bufB, H1, N, H1 / 16);
  {
    int grid = ((N + 3) / 4) * 8;          // SPAN=1: grp covers 4 rows
    spmm8_kernel<8><<<grid, 256, 0, stream>>>(
        row_start, ecv, bufB, H1, mask1, mm1, bufC, N);
  }
  // layer 2: GEMM(H1->H2) -> SpMM v8 (D=128, 4 slices, act+mask2)
  gemm_breg_kernel<8><<<GEMM_BLOCKS, 256, 0, stream>>>(
      bufC, w2hi, w2lo, biasf + H1, bufB, H2, N, H2 / 16);
  {
    int grid = ((N + 7) / 8) * 8;          // SPAN=2: grp covers 8 rows
    spmm8_kernel<4><<<grid, 256, 0, stream>>>(
        row_start, ecv, bufB, H2, mask2, mm2, bufA, N);
  }
  // layer 3: GEMM(H2->OUT) -> SpMM v7 (D=64, plain) -> f32 d_out
  gemm_breg_kernel<4><<<GEMM_BLOCKS, 256, 0, stream>>>(
      bufA, w3hi, w3lo, biasf + H1 + H2, bufB, OUT, N, OUT / 16);
  spmm7_kernel<0, 1><<<(N + 3) / 4, 256, 0, stream>>>(
      row_start, ecv, bufB, OUT, nullptr, fmode, d_out, N);
}

// Round 13
// 527.590 us; speedup vs baseline: 1.3431x; 1.3431x over previous
//
#include <hip/hip_runtime.h>

// ===========================================================================
// ViewGCNEncoder r13 = r11 (best, 502us) + fixes:
//  (1) GEMM_BLOCKS 2048->1536: at 80 VGPR only 6 waves/SIMD fit -> 1536
//      co-resident blocks; the extra 512 ran as a ~25%-util straggler round
//      (r11 occupancy 28%).
//  (2) masks bit-packed once (2.4MB, L2-resident) -> removes 51+25MB of
//      i32-mask L2-fill from the two masked SpMMs (visible in FETCH).
//  (3) one memset for cnt+fill.
// r12's XCD column slicing reverted (209us vs 68.5: pinning assumption failed,
// 8x edge re-read). Workspace ~87 MB (<=110 MB proven safe).
// ===========================================================================

typedef unsigned short ushort_t;
typedef __attribute__((ext_vector_type(8))) short bf16x8;   // 8 bf16 = 4 VGPRs
typedef __attribute__((ext_vector_type(4))) float f32x4;
typedef __attribute__((ext_vector_type(2))) unsigned int u32x2;

__device__ __forceinline__ float bf2f(ushort_t u) {
  return __uint_as_float(((unsigned int)u) << 16);
}
__device__ __forceinline__ ushort_t f2bf(float f) {
  unsigned int u = __float_as_uint(f);
  return (ushort_t)((u + 0x7FFFu + ((u >> 16) & 1u)) >> 16);  // RNE
}
__device__ __forceinline__ float read_f(const void* p, int fm, size_t i) {
  return fm ? bf2f(((const ushort_t*)p)[i]) : ((const float*)p)[i];
}

// ---------------- fused dtype sniff (frozen) ----------------
__global__ void sniff_all_kernel(const void* __restrict__ x,
                                 const void* __restrict__ m1,
                                 const void* __restrict__ m2,
                                 int* __restrict__ modes) {
  if (blockIdx.x == 0) {
    __shared__ int bfok;
    if (threadIdx.x == 0) bfok = 1;
    __syncthreads();
    for (int i = threadIdx.x; i < 8192; i += blockDim.x) {
      ushort_t h = ((const ushort_t*)x)[i];
      int e = (h >> 7) & 0xFF;
      if (!(h == 0 || (e >= 95 && e <= 133))) atomicAnd(&bfok, 0);
    }
    __syncthreads();
    if (threadIdx.x == 0) modes[0] = bfok;   // 1=bf16, 0=f32
  } else {
    const void* p = (blockIdx.x == 1) ? m1 : m2;
    __shared__ int ok[4];  // [i32, f32, bf16, u8]
    if (threadIdx.x < 4) ok[threadIdx.x] = 1;
    __syncthreads();
    for (int i = threadIdx.x; i < 4096; i += blockDim.x) {
      unsigned int w = ((const unsigned int*)p)[i];
      if (!(w == 0u || w == 1u)) atomicAnd(&ok[0], 0);
      if (!(w == 0u || w == 0x3F800000u)) atomicAnd(&ok[1], 0);
      unsigned int h16 = w >> 16, l16 = w & 0xFFFFu;
      if (!((h16 == 0u || h16 == 0x3F80u) && (l16 == 0u || l16 == 0x3F80u)))
        atomicAnd(&ok[2], 0);
      if (((w | (w >> 8) | (w >> 16) | (w >> 24)) & 0xFEu) != 0u) atomicAnd(&ok[3], 0);
    }
    __syncthreads();
    if (threadIdx.x == 0)
      modes[blockIdx.x] = ok[0] ? 1 : (ok[1] ? 2 : (ok[2] ? 3 : 0));
  }
}

__device__ __forceinline__ bool mask_keep(const void* mask, int mm, size_t o) {
  switch (mm) {
    case 1:  return ((const int*)mask)[o] != 0;
    case 2:  return ((const unsigned int*)mask)[o] != 0u;
    case 3:  return ((const ushort_t*)mask)[o] != 0;
    default: return ((const unsigned char*)mask)[o] != 0;
  }
}

// ---------------- mask bit-pack: one bit per element ----------------
// wave w packs elems [w*64, w*64+64) via ballot; both masks in one launch.
__global__ void bitpack_masks_kernel(const void* __restrict__ m1,
                                     const void* __restrict__ m2,
                                     const int* __restrict__ modes,
                                     unsigned long long* __restrict__ bits,
                                     int w1, int w2) {
  int gw = (blockIdx.x * blockDim.x + threadIdx.x) >> 6;
  int lane = threadIdx.x & 63;
  int nw = (gridDim.x * blockDim.x) >> 6;
  int total = w1 + w2;
  for (int w = gw; w < total; w += nw) {
    const void* m; int mm; size_t base;
    if (w < w1) { m = m1; mm = modes[1]; base = (size_t)w << 6; }
    else        { m = m2; mm = modes[2]; base = (size_t)(w - w1) << 6; }
    bool v = mask_keep(m, mm, base + lane);
    unsigned long long b = __ballot(v);
    if (lane == 0) bits[w] = b;
  }
}

// ---------------- CSR build (frozen) ----------------
__global__ void hist_kernel(const int* __restrict__ rows, int* __restrict__ cnt, int E) {
  int i = blockIdx.x * blockDim.x + threadIdx.x;
  int stride = gridDim.x * blockDim.x;
  for (; i < E; i += stride) atomicAdd(&cnt[rows[i]], 1);
}

__global__ void scan_part_kernel(const int* __restrict__ cnt, int* __restrict__ part, int n) {
  __shared__ int s[256];
  int i = blockIdx.x * 256 + threadIdx.x;
  s[threadIdx.x] = (i < n) ? cnt[i] : 0;
  __syncthreads();
  for (int off = 128; off > 0; off >>= 1) {
    if (threadIdx.x < off) s[threadIdx.x] += s[threadIdx.x + off];
    __syncthreads();
  }
  if (threadIdx.x == 0) part[blockIdx.x] = s[0];
}

__global__ __launch_bounds__(1024) void scan_top_kernel(int* __restrict__ part, int P) {
  __shared__ int s[1024];
  int t = threadIdx.x;
  int v = (t < P) ? part[t] : 0;
  s[t] = v;
  __syncthreads();
  for (int off = 1; off < 1024; off <<= 1) {
    int x = s[t];
    int y = (t >= off) ? s[t - off] : 0;
    __syncthreads();
    s[t] = x + y;
    __syncthreads();
  }
  if (t < P) part[t] = s[t] - v;   // exclusive
}

__global__ void scan_apply_kernel(const int* __restrict__ cnt, const int* __restrict__ part,
                                  int* __restrict__ row_start, int n) {
  __shared__ int s[256];
  int base = part[blockIdx.x];
  int i = blockIdx.x * 256 + threadIdx.x;
  int v = (i < n) ? cnt[i] : 0;
  s[threadIdx.x] = v;
  __syncthreads();
  for (int off = 1; off < 256; off <<= 1) {
    int x = s[threadIdx.x];
    int y = (threadIdx.x >= off) ? s[threadIdx.x - off] : 0;
    __syncthreads();
    s[threadIdx.x] = x + y;
    __syncthreads();
  }
  if (i < n) row_start[i] = base + s[threadIdx.x] - v;
  if (i == n - 1) row_start[n] = base + s[threadIdx.x];
}

__global__ void scatter_kernel(const int* __restrict__ rows, const int* __restrict__ cols,
                               const void* __restrict__ vals, const int* __restrict__ fm_p,
                               const int* __restrict__ row_start, int* __restrict__ fill,
                               int2* __restrict__ ecv, int E) {
  int fm = *fm_p;
  int i = blockIdx.x * blockDim.x + threadIdx.x;
  int stride = gridDim.x * blockDim.x;
  for (; i < E; i += stride) {
    int r = rows[i];
    int pos = atomicAdd(&fill[r], 1);
    int idx = row_start[r] + pos;
    ecv[idx] = make_int2(cols[i], __float_as_int(read_f(vals, fm, i)));
  }
}

// ---------------- fused conversions (frozen) ----------------
__global__ void split_w_all_kernel(const void* __restrict__ W1, const void* __restrict__ W2,
                                   const void* __restrict__ W3, const int* __restrict__ fm_p,
                                   ushort_t* __restrict__ whi, ushort_t* __restrict__ wlo,
                                   int n1, int n2, int n3) {
  int fm = *fm_p;
  int total = n1 + n2 + n3;
  int i = blockIdx.x * blockDim.x + threadIdx.x;
  int stride = gridDim.x * blockDim.x;
  for (; i < total; i += stride) {
    const void* src; int j;
    if (i < n1) { src = W1; j = i; }
    else if (i < n1 + n2) { src = W2; j = i - n1; }
    else { src = W3; j = i - n1 - n2; }
    float v = read_f(src, fm, j);
    ushort_t h = f2bf(v);
    whi[i] = h;
    wlo[i] = f2bf(v - bf2f(h));
  }
}

__global__ void cvt_bias_all_kernel(const void* __restrict__ b1, const void* __restrict__ b2,
                                    const void* __restrict__ b3, const int* __restrict__ fm_p,
                                    float* __restrict__ dst, int n1, int n2, int n3) {
  int fm = *fm_p;
  int i = threadIdx.x + blockIdx.x * blockDim.x;
  int total = n1 + n2 + n3;
  if (i >= total) return;
  const void* src; int j;
  if (i < n1) { src = b1; j = i; }
  else if (i < n1 + n2) { src = b2; j = i - n1; }
  else { src = b3; j = i - n1 - n2; }
  dst[i] = read_f(src, fm, j);
}

__global__ void cvt_bf16x4_kernel(const void* __restrict__ src, const int* __restrict__ fm_p,
                                  ushort_t* __restrict__ dst, int n4) {
  int fm = *fm_p;
  int i = blockIdx.x * blockDim.x + threadIdx.x;
  int stride = gridDim.x * blockDim.x;
  for (; i < n4; i += stride) {
    if (fm == 0) {
      f32x4 v = ((const f32x4*)src)[i];
      unsigned int lo = (unsigned int)f2bf(v[0]) | ((unsigned int)f2bf(v[1]) << 16);
      unsigned int hi = (unsigned int)f2bf(v[2]) | ((unsigned int)f2bf(v[3]) << 16);
      ((u32x2*)dst)[i] = (u32x2){lo, hi};
    } else {
      ((u32x2*)dst)[i] = ((const u32x2*)src)[i];
    }
  }
}

// ---------------- GEMM: W-in-registers + A-prefetch (frozen) ----------------
template<int KC>
__global__ __launch_bounds__(256) void gemm_breg_kernel(
    const ushort_t* __restrict__ A,
    const ushort_t* __restrict__ Whi, const ushort_t* __restrict__ Wlo,
    const float* __restrict__ bias, ushort_t* __restrict__ g, int ldg,
    int M, int nct) {
  const int K = KC * 32;
  int wave = threadIdx.x >> 6, lane = threadIdx.x & 63;
  int gw = blockIdx.x * 4 + wave;
  int NW = gridDim.x * 4;
  int mr = lane & 15, quad = lane >> 4;
  int ct = gw % nct;
  int nrt = (M + 15) >> 4;
  int ntasks = nct * nrt;
  if (gw >= ntasks) return;

  bf16x8 wh[KC], wl[KC];
  {
    const ushort_t* wp = Whi + (size_t)(ct * 16 + mr) * K + quad * 8;
    const ushort_t* wq = Wlo + (size_t)(ct * 16 + mr) * K + quad * 8;
#pragma unroll
    for (int kc = 0; kc < KC; ++kc) {
      wh[kc] = *(const bf16x8*)(wp + kc * 32);
      wl[kc] = *(const bf16x8*)(wq + kc * 32);
    }
  }
  int col = ct * 16 + mr;
  float bv = bias[col];

  int task = gw;
  bf16x8 af[KC];
  {
    int m = (task / nct) * 16 + mr; if (m >= M) m = M - 1;
    const ushort_t* ap = A + (size_t)m * K + quad * 8;
#pragma unroll
    for (int kc = 0; kc < KC; ++kc) af[kc] = *(const bf16x8*)(ap + kc * 32);
  }

#pragma unroll 1
  for (;;) {
    int next = task + NW;
    bool has_next = next < ntasks;
    bf16x8 afn[KC];
    if (has_next) {
      int m = (next / nct) * 16 + mr; if (m >= M) m = M - 1;
      const ushort_t* ap = A + (size_t)m * K + quad * 8;
#pragma unroll
      for (int kc = 0; kc < KC; ++kc) afn[kc] = *(const bf16x8*)(ap + kc * 32);
    }

    f32x4 acc[4];
#pragma unroll
    for (int t = 0; t < 4; ++t) acc[t] = (f32x4){0.f, 0.f, 0.f, 0.f};
#pragma unroll
    for (int kc = 0; kc < KC; ++kc) {
      acc[(2 * kc) & 3] = __builtin_amdgcn_mfma_f32_16x16x32_bf16(af[kc], wh[kc], acc[(2 * kc) & 3], 0, 0, 0);
      acc[(2 * kc + 1) & 3] = __builtin_amdgcn_mfma_f32_16x16x32_bf16(af[kc], wl[kc], acc[(2 * kc + 1) & 3], 0, 0, 0);
    }
    int m0 = (task / nct) * 16;
#pragma unroll
    for (int r = 0; r < 4; ++r) {
      int row = m0 + quad * 4 + r;
      float s = ((acc[0][r] + acc[1][r]) + (acc[2][r] + acc[3][r])) + bv;
      if (row < M) g[(size_t)row * ldg + col] = f2bf(s);
    }
    if (!has_next) break;
#pragma unroll
    for (int kc = 0; kc < KC; ++kc) af[kc] = afn[kc];
    task = next;
  }
}

// ---------------- SpMM v9: r11's spmm7 + bitmask ----------------------------
// out[r,f] = sum_e val[e]*G[col[e],f].  One wave per row, VEC elems/lane.
// Scalarized row bounds; full 8-batches + clamped tail (r11, proven).
// MODE 1: leaky(0.2) + BITMASK dropout -> bf16.  MODE 0: plain -> f32 out.
template<int MODE, int VEC>
__global__ __launch_bounds__(256) void spmm9_kernel(
    const int* __restrict__ row_start, const int2* __restrict__ ecv,
    const ushort_t* __restrict__ G, int D,
    const unsigned long long* __restrict__ mbits,
    void* __restrict__ outp, int N) {
  int wave = threadIdx.x >> 6, lane = threadIdx.x & 63;
  int r = blockIdx.x * 4 + wave;
  if (r >= N) return;
  int f0 = lane * VEC;
  int e  = __builtin_amdgcn_readfirstlane(row_start[r]);
  int e1 = __builtin_amdgcn_readfirstlane(row_start[r + 1]);
  float a[VEC];
#pragma unroll
  for (int q = 0; q < VEC; ++q) a[q] = 0.f;

  for (; e + 8 <= e1; e += 8) {
    int2 cv[8];
#pragma unroll
    for (int j = 0; j < 8; ++j) cv[j] = ecv[e + j];
    if (VEC == 4) {
      u32x2 gg[8];
#pragma unroll
      for (int j = 0; j < 8; ++j)
        gg[j] = *(const u32x2*)(G + (size_t)cv[j].x * D + f0);
#pragma unroll
      for (int j = 0; j < 8; ++j) {
        float v = __int_as_float(cv[j].y);
        a[0] += v * bf2f((ushort_t)gg[j][0]);
        a[1] += v * bf2f((ushort_t)(gg[j][0] >> 16));
        a[2] += v * bf2f((ushort_t)gg[j][1]);
        a[3] += v * bf2f((ushort_t)(gg[j][1] >> 16));
      }
    } else if (VEC == 2) {
      unsigned int gg[8];
#pragma unroll
      for (int j = 0; j < 8; ++j)
        gg[j] = *(const unsigned int*)(G + (size_t)cv[j].x * D + f0);
#pragma unroll
      for (int j = 0; j < 8; ++j) {
        float v = __int_as_float(cv[j].y);
        a[0] += v * bf2f((ushort_t)gg[j]);
        a[1] += v * bf2f((ushort_t)(gg[j] >> 16));
      }
    } else {
      ushort_t h[8];
#pragma unroll
      for (int j = 0; j < 8; ++j) h[j] = G[(size_t)cv[j].x * D + f0];
#pragma unroll
      for (int j = 0; j < 8; ++j) a[0] += __int_as_float(cv[j].y) * bf2f(h[j]);
    }
  }
  if (e < e1) {
    int idx[8]; float v[8];
#pragma unroll
    for (int j = 0; j < 8; ++j) {
      int ee = e + j;
      bool ok = ee < e1;
      int2 cv = ecv[ok ? ee : e1 - 1];
      idx[j] = cv.x;
      v[j] = ok ? __int_as_float(cv.y) : 0.f;
    }
    if (VEC == 4) {
      u32x2 gg[8];
#pragma unroll
      for (int j = 0; j < 8; ++j)
        gg[j] = *(const u32x2*)(G + (size_t)idx[j] * D + f0);
#pragma unroll
      for (int j = 0; j < 8; ++j) {
        a[0] += v[j] * bf2f((ushort_t)gg[j][0]);
        a[1] += v[j] * bf2f((ushort_t)(gg[j][0] >> 16));
        a[2] += v[j] * bf2f((ushort_t)gg[j][1]);
        a[3] += v[j] * bf2f((ushort_t)(gg[j][1] >> 16));
      }
    } else if (VEC == 2) {
      unsigned int gg[8];
#pragma unroll
      for (int j = 0; j < 8; ++j)
        gg[j] = *(const unsigned int*)(G + (size_t)idx[j] * D + f0);
#pragma unroll
      for (int j = 0; j < 8; ++j) {
        a[0] += v[j] * bf2f((ushort_t)gg[j]);
        a[1] += v[j] * bf2f((ushort_t)(gg[j] >> 16));
      }
    } else {
      ushort_t h[8];
#pragma unroll
      for (int j = 0; j < 8; ++j) h[j] = G[(size_t)idx[j] * D + f0];
#pragma unroll
      for (int j = 0; j < 8; ++j) a[0] += v[j] * bf2f(h[j]);
    }
  }

  size_t o = (size_t)r * D + f0;
  if (MODE == 1) {
    unsigned long long bw = mbits[o >> 6];   // VEC<=4 bits share one word
    int sh = (int)(o & 63);
    ushort_t pk[VEC];
#pragma unroll
    for (int q = 0; q < VEC; ++q) {
      float t = a[q];
      t = (t >= 0.f) ? t : 0.2f * t;                       // leaky relu 0.2
      t = ((bw >> (sh + q)) & 1ull) ? t * 1.25f : 0.f;     // keep = 1/0.8
      pk[q] = f2bf(t);
    }
    if (VEC == 4) {
      u32x2 w;
      w[0] = (unsigned int)pk[0] | ((unsigned int)pk[1] << 16);
      w[1] = (unsigned int)pk[2] | ((unsigned int)pk[3] << 16);
      *(u32x2*)((ushort_t*)outp + o) = w;
    } else if (VEC == 2) {
      *(unsigned int*)((ushort_t*)outp + o) =
          (unsigned int)pk[0] | ((unsigned int)pk[1] << 16);
    } else {
      ((ushort_t*)outp)[o] = pk[0];
    }
  } else {
#pragma unroll
    for (int q = 0; q < VEC; ++q) ((float*)outp)[o + q] = a[q];
  }
}

// ---------------- launch ----------------
extern "C" void kernel_launch(void* const* d_in, const int* in_sizes, int n_in,
                              void* d_out, int out_size, void* d_ws, size_t ws_size,
                              hipStream_t stream) {
  const void* x     = d_in[0];
  const int*  rows  = (const int*)d_in[1];
  const int*  cols  = (const int*)d_in[2];
  const void* vals  = d_in[3];
  const void* W1    = d_in[4];
  const void* b1    = d_in[5];
  const void* W2    = d_in[6];
  const void* b2    = d_in[7];
  const void* W3    = d_in[8];
  const void* b3    = d_in[9];
  const void* mask1 = d_in[10];
  const void* mask2 = d_in[11];

  const int H1  = in_sizes[5];            // 256
  const int H2  = in_sizes[7];            // 128
  const int OUT = in_sizes[9];            // 64
  const int IN  = in_sizes[4] / H1;       // 256
  const int N   = in_sizes[0] / IN;       // 50000
  const int E   = in_sizes[1];            // 800000
  const int W1n = in_sizes[4], W2n = in_sizes[6], W3n = in_sizes[8];
  const int MW1 = (N * H1) >> 6;          // mask1 64-bit words
  const int MW2 = (N * H2) >> 6;          // mask2 64-bit words

  char* ws = (char*)d_ws;
  size_t off = 0;
  auto alloc = [&](size_t bytes) -> void* {
    void* p = ws + off;
    off = (off + bytes + 255) & ~(size_t)255;
    return p;
  };
  int*      modes     = (int*)alloc(4 * 4);
  int*      row_start = (int*)alloc((size_t)(N + 1) * 4);
  int*      cnt       = (int*)alloc((size_t)N * 8);   // [cnt | fill], one memset
  int*      part      = (int*)alloc(1024 * 4);
  unsigned long long* mbits = (unsigned long long*)alloc((size_t)(MW1 + MW2) * 8);
  int2*     ecv       = (int2*)alloc((size_t)E * 8);
  ushort_t* whi       = (ushort_t*)alloc((size_t)(W1n + W2n + W3n) * 2);
  ushort_t* wlo       = (ushort_t*)alloc((size_t)(W1n + W2n + W3n) * 2);
  float*    biasf     = (float*)alloc((size_t)(H1 + H2 + OUT) * 4);
  ushort_t* bufA      = (ushort_t*)alloc((size_t)N * H1 * 2);   // 25.6 MB
  ushort_t* bufB      = (ushort_t*)alloc((size_t)N * H1 * 2);   // 25.6 MB
  ushort_t* bufC      = (ushort_t*)alloc((size_t)N * H1 * 2);   // 25.6 MB
  // total ~87 MB (<=110 MB proven safe in r3)

  int* fmode = modes;
  int* fill  = cnt + N;
  ushort_t* w1hi = whi,             *w1lo = wlo;
  ushort_t* w2hi = whi + W1n,       *w2lo = wlo + W1n;
  ushort_t* w3hi = whi + W1n + W2n, *w3lo = wlo + W1n + W2n;

  sniff_all_kernel<<<3, 256, 0, stream>>>(x, mask1, mask2, modes);

  // CSR build with parallel scan (single memset covers cnt+fill)
  const int P = (N + 255) / 256;
  hipMemsetAsync(cnt, 0, (size_t)N * 8, stream);
  hist_kernel<<<1024, 256, 0, stream>>>(rows, cnt, E);
  scan_part_kernel<<<P, 256, 0, stream>>>(cnt, part, N);
  scan_top_kernel<<<1, 1024, 0, stream>>>(part, P);
  scan_apply_kernel<<<P, 256, 0, stream>>>(cnt, part, row_start, N);
  scatter_kernel<<<1024, 256, 0, stream>>>(rows, cols, vals, fmode, row_start, fill, ecv, E);

  // conversions + mask bitpack
  int wtot = W1n + W2n + W3n;
  split_w_all_kernel<<<(wtot + 255) / 256, 256, 0, stream>>>(
      W1, W2, W3, fmode, whi, wlo, W1n, W2n, W3n);
  cvt_bias_all_kernel<<<(H1 + H2 + OUT + 255) / 256, 256, 0, stream>>>(
      b1, b2, b3, fmode, biasf, H1, H2, OUT);
  cvt_bf16x4_kernel<<<2048, 256, 0, stream>>>(x, fmode, bufA, (N * IN) / 4);
  bitpack_masks_kernel<<<2048, 256, 0, stream>>>(mask1, mask2, modes, mbits, MW1, MW2);

  // 6 blocks/CU x 256 CUs: all co-resident at 80 VGPR (6 waves/SIMD cap).
  const int GEMM_BLOCKS = 1536;            // 6144 waves; % {16,8,4} == 0
  int spmm_grid = (N + 3) / 4;

  // layer 1: GEMM(IN->H1) -> SpMM(D=256, VEC=4, act+mask1 bits)
  gemm_breg_kernel<8><<<GEMM_BLOCKS, 256, 0, stream>>>(
      bufA, w1hi, w1lo, biasf, bufB, H1, N, H1 / 16);
  spmm9_kernel<1, 4><<<spmm_grid, 256, 0, stream>>>(
      row_start, ecv, bufB, H1, mbits, bufC, N);
  // layer 2: GEMM(H1->H2) -> SpMM(D=128, VEC=2, act+mask2 bits)
  gemm_breg_kernel<8><<<GEMM_BLOCKS, 256, 0, stream>>>(
      bufC, w2hi, w2lo, biasf + H1, bufB, H2, N, H2 / 16);
  spmm9_kernel<1, 2><<<spmm_grid, 256, 0, stream>>>(
      row_start, ecv, bufB, H2, mbits + MW1, bufA, N);
  // layer 3: GEMM(H2->OUT) -> SpMM(D=64, VEC=1, plain) -> f32 d_out
  gemm_breg_kernel<4><<<GEMM_BLOCKS, 256, 0, stream>>>(
      bufA, w3hi, w3lo, biasf + H1 + H2, bufB, OUT, N, OUT / 16);
  spmm9_kernel<0, 1><<<spmm_grid, 256, 0, stream>>>(
      row_start, ecv, bufB, OUT, nullptr, d_out, N);
}

// Round 14
// 477.912 us; speedup vs baseline: 1.4828x; 1.1039x over previous
//
#include <hip/hip_runtime.h>

// ===========================================================================
// ViewGCNEncoder r14 = r11-core (proven spmm7, direct masks) + launch fusion:
//  - bitpack dropped (r13 lesson: it only MOVED the 77MB mask read, +40us).
//  - prep kernel = sniff + cnt/fill zeroing (replaces sniff + memset).
//  - convert kernel = W-split + bias + x->bf16 in one grid-stride launch.
//  - GEMM_BLOCKS 1024 (trend: 2048->68.3us, 1536->62.5us; ~3-4 blocks/CU
//    co-resident at the real ~160-reg class).
// 13 launches (was 17). Workspace ~84 MB (<=110 MB proven safe).
// ===========================================================================

typedef unsigned short ushort_t;
typedef __attribute__((ext_vector_type(8))) short bf16x8;   // 8 bf16 = 4 VGPRs
typedef __attribute__((ext_vector_type(4))) float f32x4;
typedef __attribute__((ext_vector_type(2))) unsigned int u32x2;

__device__ __forceinline__ float bf2f(ushort_t u) {
  return __uint_as_float(((unsigned int)u) << 16);
}
__device__ __forceinline__ ushort_t f2bf(float f) {
  unsigned int u = __float_as_uint(f);
  return (ushort_t)((u + 0x7FFFu + ((u >> 16) & 1u)) >> 16);  // RNE
}
__device__ __forceinline__ float read_f(const void* p, int fm, size_t i) {
  return fm ? bf2f(((const ushort_t*)p)[i]) : ((const float*)p)[i];
}

__device__ __forceinline__ bool mask_keep(const void* mask, int mm, size_t o) {
  switch (mm) {
    case 1:  return ((const int*)mask)[o] != 0;
    case 2:  return ((const unsigned int*)mask)[o] != 0u;
    case 3:  return ((const ushort_t*)mask)[o] != 0;
    default: return ((const unsigned char*)mask)[o] != 0;
  }
}

// ---------------- prep: dtype sniff (blocks 0-2) + zero cnt/fill (blocks 3+)
__global__ void prep_kernel(const void* __restrict__ x,
                            const void* __restrict__ m1,
                            const void* __restrict__ m2,
                            int* __restrict__ modes,
                            int* __restrict__ zero_region, int zn) {
  if (blockIdx.x == 0) {
    __shared__ int bfok;
    if (threadIdx.x == 0) bfok = 1;
    __syncthreads();
    for (int i = threadIdx.x; i < 8192; i += blockDim.x) {
      ushort_t h = ((const ushort_t*)x)[i];
      int e = (h >> 7) & 0xFF;
      if (!(h == 0 || (e >= 95 && e <= 133))) atomicAnd(&bfok, 0);
    }
    __syncthreads();
    if (threadIdx.x == 0) modes[0] = bfok;   // 1=bf16, 0=f32
  } else if (blockIdx.x <= 2) {
    const void* p = (blockIdx.x == 1) ? m1 : m2;
    __shared__ int ok[4];  // [i32, f32, bf16, u8]
    if (threadIdx.x < 4) ok[threadIdx.x] = 1;
    __syncthreads();
    for (int i = threadIdx.x; i < 4096; i += blockDim.x) {
      unsigned int w = ((const unsigned int*)p)[i];
      if (!(w == 0u || w == 1u)) atomicAnd(&ok[0], 0);
      if (!(w == 0u || w == 0x3F800000u)) atomicAnd(&ok[1], 0);
      unsigned int h16 = w >> 16, l16 = w & 0xFFFFu;
      if (!((h16 == 0u || h16 == 0x3F80u) && (l16 == 0u || l16 == 0x3F80u)))
        atomicAnd(&ok[2], 0);
      if (((w | (w >> 8) | (w >> 16) | (w >> 24)) & 0xFEu) != 0u) atomicAnd(&ok[3], 0);
    }
    __syncthreads();
    if (threadIdx.x == 0)
      modes[blockIdx.x] = ok[0] ? 1 : (ok[1] ? 2 : (ok[2] ? 3 : 0));
  } else {
    int i = (blockIdx.x - 3) * blockDim.x + threadIdx.x;
    int stride = (gridDim.x - 3) * blockDim.x;
    for (; i < zn; i += stride) zero_region[i] = 0;
  }
}

// ---------------- CSR build (frozen) ----------------
__global__ void hist_kernel(const int* __restrict__ rows, int* __restrict__ cnt, int E) {
  int i = blockIdx.x * blockDim.x + threadIdx.x;
  int stride = gridDim.x * blockDim.x;
  for (; i < E; i += stride) atomicAdd(&cnt[rows[i]], 1);
}

__global__ void scan_part_kernel(const int* __restrict__ cnt, int* __restrict__ part, int n) {
  __shared__ int s[256];
  int i = blockIdx.x * 256 + threadIdx.x;
  s[threadIdx.x] = (i < n) ? cnt[i] : 0;
  __syncthreads();
  for (int off = 128; off > 0; off >>= 1) {
    if (threadIdx.x < off) s[threadIdx.x] += s[threadIdx.x + off];
    __syncthreads();
  }
  if (threadIdx.x == 0) part[blockIdx.x] = s[0];
}

__global__ __launch_bounds__(1024) void scan_top_kernel(int* __restrict__ part, int P) {
  __shared__ int s[1024];
  int t = threadIdx.x;
  int v = (t < P) ? part[t] : 0;
  s[t] = v;
  __syncthreads();
  for (int off = 1; off < 1024; off <<= 1) {
    int x = s[t];
    int y = (t >= off) ? s[t - off] : 0;
    __syncthreads();
    s[t] = x + y;
    __syncthreads();
  }
  if (t < P) part[t] = s[t] - v;   // exclusive
}

__global__ void scan_apply_kernel(const int* __restrict__ cnt, const int* __restrict__ part,
                                  int* __restrict__ row_start, int n) {
  __shared__ int s[256];
  int base = part[blockIdx.x];
  int i = blockIdx.x * 256 + threadIdx.x;
  int v = (i < n) ? cnt[i] : 0;
  s[threadIdx.x] = v;
  __syncthreads();
  for (int off = 1; off < 256; off <<= 1) {
    int x = s[threadIdx.x];
    int y = (threadIdx.x >= off) ? s[threadIdx.x - off] : 0;
    __syncthreads();
    s[threadIdx.x] = x + y;
    __syncthreads();
  }
  if (i < n) row_start[i] = base + s[threadIdx.x] - v;
  if (i == n - 1) row_start[n] = base + s[threadIdx.x];
}

__global__ void scatter_kernel(const int* __restrict__ rows, const int* __restrict__ cols,
                               const void* __restrict__ vals, const int* __restrict__ fm_p,
                               const int* __restrict__ row_start, int* __restrict__ fill,
                               int2* __restrict__ ecv, int E) {
  int fm = *fm_p;
  int i = blockIdx.x * blockDim.x + threadIdx.x;
  int stride = gridDim.x * blockDim.x;
  for (; i < E; i += stride) {
    int r = rows[i];
    int pos = atomicAdd(&fill[r], 1);
    int idx = row_start[r] + pos;
    ecv[idx] = make_int2(cols[i], __float_as_int(read_f(vals, fm, i)));
  }
}

// ---------------- convert: W hi/lo split + bias + x->bf16, one launch -------
__global__ void convert_all_kernel(
    const void* __restrict__ W1, const void* __restrict__ W2, const void* __restrict__ W3,
    const void* __restrict__ b1, const void* __restrict__ b2, const void* __restrict__ b3,
    const void* __restrict__ x, const int* __restrict__ fm_p,
    ushort_t* __restrict__ whi, ushort_t* __restrict__ wlo,
    float* __restrict__ biasf, ushort_t* __restrict__ xbf,
    int n1, int n2, int n3, int h1, int h2, int h3, int nx4) {
  int fm = *fm_p;
  int wtot = n1 + n2 + n3;
  int btot = h1 + h2 + h3;
  int total = wtot + btot + nx4;
  int i = blockIdx.x * blockDim.x + threadIdx.x;
  int stride = gridDim.x * blockDim.x;
  for (; i < total; i += stride) {
    if (i < wtot) {
      const void* src; int j;
      if (i < n1) { src = W1; j = i; }
      else if (i < n1 + n2) { src = W2; j = i - n1; }
      else { src = W3; j = i - n1 - n2; }
      float v = read_f(src, fm, j);
      ushort_t h = f2bf(v);
      whi[i] = h;
      wlo[i] = f2bf(v - bf2f(h));
    } else if (i < wtot + btot) {
      int k = i - wtot;
      const void* src; int j;
      if (k < h1) { src = b1; j = k; }
      else if (k < h1 + h2) { src = b2; j = k - h1; }
      else { src = b3; j = k - h1 - h2; }
      biasf[k] = read_f(src, fm, j);
    } else {
      int k = i - wtot - btot;          // 4-wide x conversion
      if (fm == 0) {
        f32x4 v = ((const f32x4*)x)[k];
        unsigned int lo = (unsigned int)f2bf(v[0]) | ((unsigned int)f2bf(v[1]) << 16);
        unsigned int hi = (unsigned int)f2bf(v[2]) | ((unsigned int)f2bf(v[3]) << 16);
        ((u32x2*)xbf)[k] = (u32x2){lo, hi};
      } else {
        ((u32x2*)xbf)[k] = ((const u32x2*)x)[k];
      }
    }
  }
}

// ---------------- GEMM: W-in-registers + A-prefetch (frozen) ----------------
template<int KC>
__global__ __launch_bounds__(256) void gemm_breg_kernel(
    const ushort_t* __restrict__ A,
    const ushort_t* __restrict__ Whi, const ushort_t* __restrict__ Wlo,
    const float* __restrict__ bias, ushort_t* __restrict__ g, int ldg,
    int M, int nct) {
  const int K = KC * 32;
  int wave = threadIdx.x >> 6, lane = threadIdx.x & 63;
  int gw = blockIdx.x * 4 + wave;
  int NW = gridDim.x * 4;
  int mr = lane & 15, quad = lane >> 4;
  int ct = gw % nct;
  int nrt = (M + 15) >> 4;
  int ntasks = nct * nrt;
  if (gw >= ntasks) return;

  bf16x8 wh[KC], wl[KC];
  {
    const ushort_t* wp = Whi + (size_t)(ct * 16 + mr) * K + quad * 8;
    const ushort_t* wq = Wlo + (size_t)(ct * 16 + mr) * K + quad * 8;
#pragma unroll
    for (int kc = 0; kc < KC; ++kc) {
      wh[kc] = *(const bf16x8*)(wp + kc * 32);
      wl[kc] = *(const bf16x8*)(wq + kc * 32);
    }
  }
  int col = ct * 16 + mr;
  float bv = bias[col];

  int task = gw;
  bf16x8 af[KC];
  {
    int m = (task / nct) * 16 + mr; if (m >= M) m = M - 1;
    const ushort_t* ap = A + (size_t)m * K + quad * 8;
#pragma unroll
    for (int kc = 0; kc < KC; ++kc) af[kc] = *(const bf16x8*)(ap + kc * 32);
  }

#pragma unroll 1
  for (;;) {
    int next = task + NW;
    bool has_next = next < ntasks;
    bf16x8 afn[KC];
    if (has_next) {
      int m = (next / nct) * 16 + mr; if (m >= M) m = M - 1;
      const ushort_t* ap = A + (size_t)m * K + quad * 8;
#pragma unroll
      for (int kc = 0; kc < KC; ++kc) afn[kc] = *(const bf16x8*)(ap + kc * 32);
    }

    f32x4 acc[4];
#pragma unroll
    for (int t = 0; t < 4; ++t) acc[t] = (f32x4){0.f, 0.f, 0.f, 0.f};
#pragma unroll
    for (int kc = 0; kc < KC; ++kc) {
      acc[(2 * kc) & 3] = __builtin_amdgcn_mfma_f32_16x16x32_bf16(af[kc], wh[kc], acc[(2 * kc) & 3], 0, 0, 0);
      acc[(2 * kc + 1) & 3] = __builtin_amdgcn_mfma_f32_16x16x32_bf16(af[kc], wl[kc], acc[(2 * kc + 1) & 3], 0, 0, 0);
    }
    int m0 = (task / nct) * 16;
#pragma unroll
    for (int r = 0; r < 4; ++r) {
      int row = m0 + quad * 4 + r;
      float s = ((acc[0][r] + acc[1][r]) + (acc[2][r] + acc[3][r])) + bv;
      if (row < M) g[(size_t)row * ldg + col] = f2bf(s);
    }
    if (!has_next) break;
#pragma unroll
    for (int kc = 0; kc < KC; ++kc) af[kc] = afn[kc];
    task = next;
  }
}

// ---------------- SpMM v7 (r11 exact, proven best) --------------------------
// out[r,f] = sum_e val[e]*G[col[e],f].  One wave per row, VEC elems/lane.
// Scalarized row bounds; full 8-batches + clamped tail.
// MODE 1: leaky(0.2)+mask -> bf16.  MODE 0: plain -> f32 (final out).
template<int MODE, int VEC>
__global__ __launch_bounds__(256) void spmm7_kernel(
    const int* __restrict__ row_start, const int2* __restrict__ ecv,
    const ushort_t* __restrict__ G, int D,
    const void* __restrict__ mask, const int* __restrict__ mmode_p,
    void* __restrict__ outp, int N) {
  int wave = threadIdx.x >> 6, lane = threadIdx.x & 63;
  int r = blockIdx.x * 4 + wave;
  if (r >= N) return;
  int f0 = lane * VEC;
  int e  = __builtin_amdgcn_readfirstlane(row_start[r]);
  int e1 = __builtin_amdgcn_readfirstlane(row_start[r + 1]);
  float a[VEC];
#pragma unroll
  for (int q = 0; q < VEC; ++q) a[q] = 0.f;

  for (; e + 8 <= e1; e += 8) {
    int2 cv[8];
#pragma unroll
    for (int j = 0; j < 8; ++j) cv[j] = ecv[e + j];
    if (VEC == 4) {
      u32x2 gg[8];
#pragma unroll
      for (int j = 0; j < 8; ++j)
        gg[j] = *(const u32x2*)(G + (size_t)cv[j].x * D + f0);
#pragma unroll
      for (int j = 0; j < 8; ++j) {
        float v = __int_as_float(cv[j].y);
        a[0] += v * bf2f((ushort_t)gg[j][0]);
        a[1] += v * bf2f((ushort_t)(gg[j][0] >> 16));
        a[2] += v * bf2f((ushort_t)gg[j][1]);
        a[3] += v * bf2f((ushort_t)(gg[j][1] >> 16));
      }
    } else if (VEC == 2) {
      unsigned int gg[8];
#pragma unroll
      for (int j = 0; j < 8; ++j)
        gg[j] = *(const unsigned int*)(G + (size_t)cv[j].x * D + f0);
#pragma unroll
      for (int j = 0; j < 8; ++j) {
        float v = __int_as_float(cv[j].y);
        a[0] += v * bf2f((ushort_t)gg[j]);
        a[1] += v * bf2f((ushort_t)(gg[j] >> 16));
      }
    } else {
      ushort_t h[8];
#pragma unroll
      for (int j = 0; j < 8; ++j) h[j] = G[(size_t)cv[j].x * D + f0];
#pragma unroll
      for (int j = 0; j < 8; ++j) a[0] += __int_as_float(cv[j].y) * bf2f(h[j]);
    }
  }
  if (e < e1) {
    int idx[8]; float v[8];
#pragma unroll
    for (int j = 0; j < 8; ++j) {
      int ee = e + j;
      bool ok = ee < e1;
      int2 cv = ecv[ok ? ee : e1 - 1];
      idx[j] = cv.x;
      v[j] = ok ? __int_as_float(cv.y) : 0.f;
    }
    if (VEC == 4) {
      u32x2 gg[8];
#pragma unroll
      for (int j = 0; j < 8; ++j)
        gg[j] = *(const u32x2*)(G + (size_t)idx[j] * D + f0);
#pragma unroll
      for (int j = 0; j < 8; ++j) {
        a[0] += v[j] * bf2f((ushort_t)gg[j][0]);
        a[1] += v[j] * bf2f((ushort_t)(gg[j][0] >> 16));
        a[2] += v[j] * bf2f((ushort_t)gg[j][1]);
        a[3] += v[j] * bf2f((ushort_t)(gg[j][1] >> 16));
      }
    } else if (VEC == 2) {
      unsigned int gg[8];
#pragma unroll
      for (int j = 0; j < 8; ++j)
        gg[j] = *(const unsigned int*)(G + (size_t)idx[j] * D + f0);
#pragma unroll
      for (int j = 0; j < 8; ++j) {
        a[0] += v[j] * bf2f((ushort_t)gg[j]);
        a[1] += v[j] * bf2f((ushort_t)(gg[j] >> 16));
      }
    } else {
      ushort_t h[8];
#pragma unroll
      for (int j = 0; j < 8; ++j) h[j] = G[(size_t)idx[j] * D + f0];
#pragma unroll
      for (int j = 0; j < 8; ++j) a[0] += v[j] * bf2f(h[j]);
    }
  }

  size_t o = (size_t)r * D + f0;
  if (MODE == 1) {
    int mm = *mmode_p;
    ushort_t pk[VEC];
#pragma unroll
    for (int q = 0; q < VEC; ++q) {
      float t = a[q];
      t = (t >= 0.f) ? t : 0.2f * t;                     // leaky relu 0.2
      t = mask_keep(mask, mm, o + q) ? t * 1.25f : 0.f;  // keep = 1/(1-0.2)
      pk[q] = f2bf(t);
    }
    if (VEC == 4) {
      u32x2 w;
      w[0] = (unsigned int)pk[0] | ((unsigned int)pk[1] << 16);
      w[1] = (unsigned int)pk[2] | ((unsigned int)pk[3] << 16);
      *(u32x2*)((ushort_t*)outp + o) = w;
    } else if (VEC == 2) {
      *(unsigned int*)((ushort_t*)outp + o) =
          (unsigned int)pk[0] | ((unsigned int)pk[1] << 16);
    } else {
      ((ushort_t*)outp)[o] = pk[0];
    }
  } else {
#pragma unroll
    for (int q = 0; q < VEC; ++q) ((float*)outp)[o + q] = a[q];
  }
}

// ---------------- launch ----------------
extern "C" void kernel_launch(void* const* d_in, const int* in_sizes, int n_in,
                              void* d_out, int out_size, void* d_ws, size_t ws_size,
                              hipStream_t stream) {
  const void* x     = d_in[0];
  const int*  rows  = (const int*)d_in[1];
  const int*  cols  = (const int*)d_in[2];
  const void* vals  = d_in[3];
  const void* W1    = d_in[4];
  const void* b1    = d_in[5];
  const void* W2    = d_in[6];
  const void* b2    = d_in[7];
  const void* W3    = d_in[8];
  const void* b3    = d_in[9];
  const void* mask1 = d_in[10];
  const void* mask2 = d_in[11];

  const int H1  = in_sizes[5];            // 256
  const int H2  = in_sizes[7];            // 128
  const int OUT = in_sizes[9];            // 64
  const int IN  = in_sizes[4] / H1;       // 256
  const int N   = in_sizes[0] / IN;       // 50000
  const int E   = in_sizes[1];            // 800000
  const int W1n = in_sizes[4], W2n = in_sizes[6], W3n = in_sizes[8];

  char* ws = (char*)d_ws;
  size_t off = 0;
  auto alloc = [&](size_t bytes) -> void* {
    void* p = ws + off;
    off = (off + bytes + 255) & ~(size_t)255;
    return p;
  };
  int*      modes     = (int*)alloc(4 * 4);
  int*      row_start = (int*)alloc((size_t)(N + 1) * 4);
  int*      cnt       = (int*)alloc((size_t)N * 8);   // [cnt | fill]
  int*      part      = (int*)alloc(1024 * 4);
  int2*     ecv       = (int2*)alloc((size_t)E * 8);
  ushort_t* whi       = (ushort_t*)alloc((size_t)(W1n + W2n + W3n) * 2);
  ushort_t* wlo       = (ushort_t*)alloc((size_t)(W1n + W2n + W3n) * 2);
  float*    biasf     = (float*)alloc((size_t)(H1 + H2 + OUT) * 4);
  ushort_t* bufA      = (ushort_t*)alloc((size_t)N * H1 * 2);   // 25.6 MB
  ushort_t* bufB      = (ushort_t*)alloc((size_t)N * H1 * 2);   // 25.6 MB
  ushort_t* bufC      = (ushort_t*)alloc((size_t)N * H1 * 2);   // 25.6 MB
  // total ~84 MB (<=110 MB proven safe in r3)

  int* fmode = modes;
  int* mm1   = modes + 1;
  int* mm2   = modes + 2;
  int* fill  = cnt + N;
  ushort_t* w1hi = whi,             *w1lo = wlo;
  ushort_t* w2hi = whi + W1n,       *w2lo = wlo + W1n;
  ushort_t* w3hi = whi + W1n + W2n, *w3lo = wlo + W1n + W2n;

  // prep: sniff (3 blocks) + zero cnt/fill
  prep_kernel<<<259, 256, 0, stream>>>(x, mask1, mask2, modes, cnt, 2 * N);

  // CSR build with parallel scan
  const int P = (N + 255) / 256;
  hist_kernel<<<1024, 256, 0, stream>>>(rows, cnt, E);
  scan_part_kernel<<<P, 256, 0, stream>>>(cnt, part, N);
  scan_top_kernel<<<1, 1024, 0, stream>>>(part, P);
  scan_apply_kernel<<<P, 256, 0, stream>>>(cnt, part, row_start, N);
  scatter_kernel<<<1024, 256, 0, stream>>>(rows, cols, vals, fmode, row_start, fill, ecv, E);

  // single conversion launch: W splits + biases + x->bf16
  convert_all_kernel<<<2048, 256, 0, stream>>>(
      W1, W2, W3, b1, b2, b3, x, fmode, whi, wlo, biasf, bufA,
      W1n, W2n, W3n, H1, H2, OUT, (N * IN) / 4);

  const int GEMM_BLOCKS = 1024;            // 4096 waves; % {16,8,4} == 0
  int spmm_grid = (N + 3) / 4;

  // layer 1: GEMM(IN->H1) -> SpMM(D=256, VEC=4, act+mask1)
  gemm_breg_kernel<8><<<GEMM_BLOCKS, 256, 0, stream>>>(
      bufA, w1hi, w1lo, biasf, bufB, H1, N, H1 / 16);
  spmm7_kernel<1, 4><<<spmm_grid, 256, 0, stream>>>(
      row_start, ecv, bufB, H1, mask1, mm1, bufC, N);
  // layer 2: GEMM(H1->H2) -> SpMM(D=128, VEC=2, act+mask2)
  gemm_breg_kernel<8><<<GEMM_BLOCKS, 256, 0, stream>>>(
      bufC, w2hi, w2lo, biasf + H1, bufB, H2, N, H2 / 16);
  spmm7_kernel<1, 2><<<spmm_grid, 256, 0, stream>>>(
      row_start, ecv, bufB, H2, mask2, mm2, bufA, N);
  // layer 3: GEMM(H2->OUT) -> SpMM(D=64, VEC=1, plain) -> f32 d_out
  gemm_breg_kernel<4><<<GEMM_BLOCKS, 256, 0, stream>>>(
      bufA, w3hi, w3lo, biasf + H1 + H2, bufB, OUT, N, OUT / 16);
  spmm7_kernel<0, 1><<<spmm_grid, 256, 0, stream>>>(
      row_start, ecv, bufB, OUT, nullptr, fmode, d_out, N);
}

// Round 15
// 453.984 us; speedup vs baseline: 1.5609x; 1.0527x over previous
//
#include <hip/hip_runtime.h>

// ===========================================================================
// ViewGCNEncoder r15 = r14 + FRAGMENT-ORDERED A buffers for all GEMMs.
// r14 evidence: gemm ~62us at 1.24 TB/s = MLP x latency cap; 80 VGPR shows
// compiler keeps no A-frags resident; each A-load spans 16 rows x 512B stride
// = 16x transaction amplification. Fix: store x-conv, spmm1-out, spmm2-out
// (and W) in MFMA fragment order -> A-frag load = base + lane*16B, one
// contiguous 1KB request. G (gather source) stays row-major.
// 13 launches. Workspace ~84 MB (<=110 MB proven safe).
// ===========================================================================

typedef unsigned short ushort_t;
typedef __attribute__((ext_vector_type(8))) short bf16x8;   // 8 bf16 = 4 VGPRs
typedef __attribute__((ext_vector_type(4))) float f32x4;
typedef __attribute__((ext_vector_type(2))) unsigned int u32x2;

__device__ __forceinline__ float bf2f(ushort_t u) {
  return __uint_as_float(((unsigned int)u) << 16);
}
__device__ __forceinline__ ushort_t f2bf(float f) {
  unsigned int u = __float_as_uint(f);
  return (ushort_t)((u + 0x7FFFu + ((u >> 16) & 1u)) >> 16);  // RNE
}
__device__ __forceinline__ float read_f(const void* p, int fm, size_t i) {
  return fm ? bf2f(((const ushort_t*)p)[i]) : ((const float*)p)[i];
}

// fragment-order offset: tile-major 16-row tiles; within tile kc-chunk(32 k)
// then lane-linear (lane = (m&15)+16*((k>>3)&3), 8 elems each).
__device__ __forceinline__ size_t frag_off(int m, int k, int K) {
  return (size_t)(m >> 4) * 16 * K + ((size_t)(k >> 5) << 9) +
         (((k >> 3) & 3) << 7) + ((m & 15) << 3) + (k & 7);
}

__device__ __forceinline__ bool mask_keep(const void* mask, int mm, size_t o) {
  switch (mm) {
    case 1:  return ((const int*)mask)[o] != 0;
    case 2:  return ((const unsigned int*)mask)[o] != 0u;
    case 3:  return ((const ushort_t*)mask)[o] != 0;
    default: return ((const unsigned char*)mask)[o] != 0;
  }
}

// ---------------- prep: dtype sniff (blocks 0-2) + zero cnt/fill (blocks 3+)
__global__ void prep_kernel(const void* __restrict__ x,
                            const void* __restrict__ m1,
                            const void* __restrict__ m2,
                            int* __restrict__ modes,
                            int* __restrict__ zero_region, int zn) {
  if (blockIdx.x == 0) {
    __shared__ int bfok;
    if (threadIdx.x == 0) bfok = 1;
    __syncthreads();
    for (int i = threadIdx.x; i < 8192; i += blockDim.x) {
      ushort_t h = ((const ushort_t*)x)[i];
      int e = (h >> 7) & 0xFF;
      if (!(h == 0 || (e >= 95 && e <= 133))) atomicAnd(&bfok, 0);
    }
    __syncthreads();
    if (threadIdx.x == 0) modes[0] = bfok;   // 1=bf16, 0=f32
  } else if (blockIdx.x <= 2) {
    const void* p = (blockIdx.x == 1) ? m1 : m2;
    __shared__ int ok[4];  // [i32, f32, bf16, u8]
    if (threadIdx.x < 4) ok[threadIdx.x] = 1;
    __syncthreads();
    for (int i = threadIdx.x; i < 4096; i += blockDim.x) {
      unsigned int w = ((const unsigned int*)p)[i];
      if (!(w == 0u || w == 1u)) atomicAnd(&ok[0], 0);
      if (!(w == 0u || w == 0x3F800000u)) atomicAnd(&ok[1], 0);
      unsigned int h16 = w >> 16, l16 = w & 0xFFFFu;
      if (!((h16 == 0u || h16 == 0x3F80u) && (l16 == 0u || l16 == 0x3F80u)))
        atomicAnd(&ok[2], 0);
      if (((w | (w >> 8) | (w >> 16) | (w >> 24)) & 0xFEu) != 0u) atomicAnd(&ok[3], 0);
    }
    __syncthreads();
    if (threadIdx.x == 0)
      modes[blockIdx.x] = ok[0] ? 1 : (ok[1] ? 2 : (ok[2] ? 3 : 0));
  } else {
    int i = (blockIdx.x - 3) * blockDim.x + threadIdx.x;
    int stride = (gridDim.x - 3) * blockDim.x;
    for (; i < zn; i += stride) zero_region[i] = 0;
  }
}

// ---------------- CSR build (frozen) ----------------
__global__ void hist_kernel(const int* __restrict__ rows, int* __restrict__ cnt, int E) {
  int i = blockIdx.x * blockDim.x + threadIdx.x;
  int stride = gridDim.x * blockDim.x;
  for (; i < E; i += stride) atomicAdd(&cnt[rows[i]], 1);
}

__global__ void scan_part_kernel(const int* __restrict__ cnt, int* __restrict__ part, int n) {
  __shared__ int s[256];
  int i = blockIdx.x * 256 + threadIdx.x;
  s[threadIdx.x] = (i < n) ? cnt[i] : 0;
  __syncthreads();
  for (int off = 128; off > 0; off >>= 1) {
    if (threadIdx.x < off) s[threadIdx.x] += s[threadIdx.x + off];
    __syncthreads();
  }
  if (threadIdx.x == 0) part[blockIdx.x] = s[0];
}

__global__ __launch_bounds__(1024) void scan_top_kernel(int* __restrict__ part, int P) {
  __shared__ int s[1024];
  int t = threadIdx.x;
  int v = (t < P) ? part[t] : 0;
  s[t] = v;
  __syncthreads();
  for (int off = 1; off < 1024; off <<= 1) {
    int x = s[t];
    int y = (t >= off) ? s[t - off] : 0;
    __syncthreads();
    s[t] = x + y;
    __syncthreads();
  }
  if (t < P) part[t] = s[t] - v;   // exclusive
}

__global__ void scan_apply_kernel(const int* __restrict__ cnt, const int* __restrict__ part,
                                  int* __restrict__ row_start, int n) {
  __shared__ int s[256];
  int base = part[blockIdx.x];
  int i = blockIdx.x * 256 + threadIdx.x;
  int v = (i < n) ? cnt[i] : 0;
  s[threadIdx.x] = v;
  __syncthreads();
  for (int off = 1; off < 256; off <<= 1) {
    int x = s[threadIdx.x];
    int y = (threadIdx.x >= off) ? s[threadIdx.x - off] : 0;
    __syncthreads();
    s[threadIdx.x] = x + y;
    __syncthreads();
  }
  if (i < n) row_start[i] = base + s[threadIdx.x] - v;
  if (i == n - 1) row_start[n] = base + s[threadIdx.x];
}

__global__ void scatter_kernel(const int* __restrict__ rows, const int* __restrict__ cols,
                               const void* __restrict__ vals, const int* __restrict__ fm_p,
                               const int* __restrict__ row_start, int* __restrict__ fill,
                               int2* __restrict__ ecv, int E) {
  int fm = *fm_p;
  int i = blockIdx.x * blockDim.x + threadIdx.x;
  int stride = gridDim.x * blockDim.x;
  for (; i < E; i += stride) {
    int r = rows[i];
    int pos = atomicAdd(&fill[r], 1);
    int idx = row_start[r] + pos;
    ecv[idx] = make_int2(cols[i], __float_as_int(read_f(vals, fm, i)));
  }
}

// ---------------- convert: W split + bias + x->bf16, ALL fragment order -----
__global__ void convert_all_kernel(
    const void* __restrict__ W1, const void* __restrict__ W2, const void* __restrict__ W3,
    const void* __restrict__ b1, const void* __restrict__ b2, const void* __restrict__ b3,
    const void* __restrict__ x, const int* __restrict__ fm_p,
    ushort_t* __restrict__ whi, ushort_t* __restrict__ wlo,
    float* __restrict__ biasf, ushort_t* __restrict__ xbf,
    int n1, int n2, int n3, int h1, int h2, int h3, int K1, int K2, int K3, int nx) {
  int fm = *fm_p;
  int wtot = n1 + n2 + n3;
  int btot = h1 + h2 + h3;
  int nx4 = nx / 4;
  int total = wtot + btot + nx4;
  int i = blockIdx.x * blockDim.x + threadIdx.x;
  int stride = gridDim.x * blockDim.x;
  for (; i < total; i += stride) {
    if (i < wtot) {
      const void* src; int j, K; size_t base;
      if (i < n1) { src = W1; j = i; K = K1; base = 0; }
      else if (i < n1 + n2) { src = W2; j = i - n1; K = K2; base = n1; }
      else { src = W3; j = i - n1 - n2; K = K3; base = (size_t)n1 + n2; }
      int n = j / K, k = j - n * K;
      float v = read_f(src, fm, j);
      ushort_t h = f2bf(v);
      size_t o = base + frag_off(n, k, K);
      whi[o] = h;
      wlo[o] = f2bf(v - bf2f(h));
    } else if (i < wtot + btot) {
      int k = i - wtot;
      const void* src; int j;
      if (k < h1) { src = b1; j = k; }
      else if (k < h1 + h2) { src = b2; j = k - h1; }
      else { src = b3; j = k - h1 - h2; }
      biasf[k] = read_f(src, fm, j);
    } else {
      int k4 = i - wtot - btot;          // 4 consecutive elems of x
      int m = k4 / (K1 / 4);
      int k0 = (k4 - m * (K1 / 4)) * 4;
      ushort_t p0, p1, p2, p3;
      if (fm == 0) {
        f32x4 v = ((const f32x4*)x)[k4];
        p0 = f2bf(v[0]); p1 = f2bf(v[1]); p2 = f2bf(v[2]); p3 = f2bf(v[3]);
      } else {
        const ushort_t* xb = (const ushort_t*)x + (size_t)k4 * 4;
        p0 = xb[0]; p1 = xb[1]; p2 = xb[2]; p3 = xb[3];
      }
      size_t o = frag_off(m, k0, K1);    // k0%4==0 -> 4 elems contiguous, 8B aligned
      *(u32x2*)(xbf + o) = (u32x2){
          (unsigned int)p0 | ((unsigned int)p1 << 16),
          (unsigned int)p2 | ((unsigned int)p3 << 16)};
    }
  }
}

// ---------------- GEMM: fragment-ordered A and W ----------------------------
// g[m,n] = sum_k A[m,k]*W[n,k] + bias[n].  A, Whi/Wlo in fragment order:
// frag load = tile_base + lane*8 elems (+kc*512) -> one contiguous 1KB/instr.
// g written row-major bf16 (feeds SpMM gathers). A-prefetch pipeline kept.
template<int KC>
__global__ __launch_bounds__(256) void gemm_breg_kernel(
    const ushort_t* __restrict__ A,
    const ushort_t* __restrict__ Whi, const ushort_t* __restrict__ Wlo,
    const float* __restrict__ bias, ushort_t* __restrict__ g, int ldg,
    int M, int nct) {
  const int K = KC * 32;
  int wave = threadIdx.x >> 6, lane = threadIdx.x & 63;
  int gw = blockIdx.x * 4 + wave;
  int NW = gridDim.x * 4;
  int mr = lane & 15, quad = lane >> 4;
  int ct = gw % nct;
  int nrt = (M + 15) >> 4;
  int ntasks = nct * nrt;
  if (gw >= ntasks) return;

  bf16x8 wh[KC], wl[KC];
  {
    const ushort_t* wp = Whi + (size_t)ct * 16 * K + lane * 8;
    const ushort_t* wq = Wlo + (size_t)ct * 16 * K + lane * 8;
#pragma unroll
    for (int kc = 0; kc < KC; ++kc) {
      wh[kc] = *(const bf16x8*)(wp + kc * 512);
      wl[kc] = *(const bf16x8*)(wq + kc * 512);
    }
  }
  int col = ct * 16 + mr;
  float bv = bias[col];

  int task = gw;
  bf16x8 af[KC];
  {
    const ushort_t* ap = A + (size_t)(task / nct) * 16 * K + lane * 8;
#pragma unroll
    for (int kc = 0; kc < KC; ++kc) af[kc] = *(const bf16x8*)(ap + kc * 512);
  }

#pragma unroll 1
  for (;;) {
    int next = task + NW;
    bool has_next = next < ntasks;
    bf16x8 afn[KC];
    if (has_next) {
      const ushort_t* ap = A + (size_t)(next / nct) * 16 * K + lane * 8;
#pragma unroll
      for (int kc = 0; kc < KC; ++kc) afn[kc] = *(const bf16x8*)(ap + kc * 512);
    }

    f32x4 acc[4];
#pragma unroll
    for (int t = 0; t < 4; ++t) acc[t] = (f32x4){0.f, 0.f, 0.f, 0.f};
#pragma unroll
    for (int kc = 0; kc < KC; ++kc) {
      acc[(2 * kc) & 3] = __builtin_amdgcn_mfma_f32_16x16x32_bf16(af[kc], wh[kc], acc[(2 * kc) & 3], 0, 0, 0);
      acc[(2 * kc + 1) & 3] = __builtin_amdgcn_mfma_f32_16x16x32_bf16(af[kc], wl[kc], acc[(2 * kc + 1) & 3], 0, 0, 0);
    }
    int m0 = (task / nct) * 16;
#pragma unroll
    for (int r = 0; r < 4; ++r) {
      int row = m0 + quad * 4 + r;
      float s = ((acc[0][r] + acc[1][r]) + (acc[2][r] + acc[3][r])) + bv;
      if (row < M) g[(size_t)row * ldg + col] = f2bf(s);
    }
    if (!has_next) break;
#pragma unroll
    for (int kc = 0; kc < KC; ++kc) af[kc] = afn[kc];
    task = next;
  }
}

// ---------------- SpMM v7f: r14 gathers, fragment-order masked output -------
// out[r,f] = sum_e val[e]*G[col[e],f].  One wave per row, VEC elems/lane.
// MODE 1: leaky+mask -> bf16 in FRAGMENT order (feeds next GEMM).
// MODE 0: plain -> f32 row-major (final d_out).
template<int MODE, int VEC>
__global__ __launch_bounds__(256) void spmm7_kernel(
    const int* __restrict__ row_start, const int2* __restrict__ ecv,
    const ushort_t* __restrict__ G, int D,
    const void* __restrict__ mask, const int* __restrict__ mmode_p,
    void* __restrict__ outp, int N) {
  int wave = threadIdx.x >> 6, lane = threadIdx.x & 63;
  int r = blockIdx.x * 4 + wave;
  if (r >= N) return;
  int f0 = lane * VEC;
  int e  = __builtin_amdgcn_readfirstlane(row_start[r]);
  int e1 = __builtin_amdgcn_readfirstlane(row_start[r + 1]);
  float a[VEC];
#pragma unroll
  for (int q = 0; q < VEC; ++q) a[q] = 0.f;

  for (; e + 8 <= e1; e += 8) {
    int2 cv[8];
#pragma unroll
    for (int j = 0; j < 8; ++j) cv[j] = ecv[e + j];
    if (VEC == 4) {
      u32x2 gg[8];
#pragma unroll
      for (int j = 0; j < 8; ++j)
        gg[j] = *(const u32x2*)(G + (size_t)cv[j].x * D + f0);
#pragma unroll
      for (int j = 0; j < 8; ++j) {
        float v = __int_as_float(cv[j].y);
        a[0] += v * bf2f((ushort_t)gg[j][0]);
        a[1] += v * bf2f((ushort_t)(gg[j][0] >> 16));
        a[2] += v * bf2f((ushort_t)gg[j][1]);
        a[3] += v * bf2f((ushort_t)(gg[j][1] >> 16));
      }
    } else if (VEC == 2) {
      unsigned int gg[8];
#pragma unroll
      for (int j = 0; j < 8; ++j)
        gg[j] = *(const unsigned int*)(G + (size_t)cv[j].x * D + f0);
#pragma unroll
      for (int j = 0; j < 8; ++j) {
        float v = __int_as_float(cv[j].y);
        a[0] += v * bf2f((ushort_t)gg[j]);
        a[1] += v * bf2f((ushort_t)(gg[j] >> 16));
      }
    } else {
      ushort_t h[8];
#pragma unroll
      for (int j = 0; j < 8; ++j) h[j] = G[(size_t)cv[j].x * D + f0];
#pragma unroll
      for (int j = 0; j < 8; ++j) a[0] += __int_as_float(cv[j].y) * bf2f(h[j]);
    }
  }
  if (e < e1) {
    int idx[8]; float v[8];
#pragma unroll
    for (int j = 0; j < 8; ++j) {
      int ee = e + j;
      bool ok = ee < e1;
      int2 cv = ecv[ok ? ee : e1 - 1];
      idx[j] = cv.x;
      v[j] = ok ? __int_as_float(cv.y) : 0.f;
    }
    if (VEC == 4) {
      u32x2 gg[8];
#pragma unroll
      for (int j = 0; j < 8; ++j)
        gg[j] = *(const u32x2*)(G + (size_t)idx[j] * D + f0);
#pragma unroll
      for (int j = 0; j < 8; ++j) {
        a[0] += v[j] * bf2f((ushort_t)gg[j][0]);
        a[1] += v[j] * bf2f((ushort_t)(gg[j][0] >> 16));
        a[2] += v[j] * bf2f((ushort_t)gg[j][1]);
        a[3] += v[j] * bf2f((ushort_t)(gg[j][1] >> 16));
      }
    } else if (VEC == 2) {
      unsigned int gg[8];
#pragma unroll
      for (int j = 0; j < 8; ++j)
        gg[j] = *(const unsigned int*)(G + (size_t)idx[j] * D + f0);
#pragma unroll
      for (int j = 0; j < 8; ++j) {
        a[0] += v[j] * bf2f((ushort_t)gg[j]);
        a[1] += v[j] * bf2f((ushort_t)(gg[j] >> 16));
      }
    } else {
      ushort_t h[8];
#pragma unroll
      for (int j = 0; j < 8; ++j) h[j] = G[(size_t)idx[j] * D + f0];
#pragma unroll
      for (int j = 0; j < 8; ++j) a[0] += v[j] * bf2f(h[j]);
    }
  }

  if (MODE == 1) {
    size_t om = (size_t)r * D + f0;      // mask is row-major
    int mm = *mmode_p;
    ushort_t pk[VEC];
#pragma unroll
    for (int q = 0; q < VEC; ++q) {
      float t = a[q];
      t = (t >= 0.f) ? t : 0.2f * t;                      // leaky relu 0.2
      t = mask_keep(mask, mm, om + q) ? t * 1.25f : 0.f;  // keep = 1/(1-0.2)
      pk[q] = f2bf(t);
    }
    // fragment-order output (feeds next GEMM's A)
    size_t o = frag_off(r, f0, D);       // VEC elems contiguous (f0%VEC==0, VEC<=4)
    if (VEC == 4) {
      *(u32x2*)((ushort_t*)outp + o) = (u32x2){
          (unsigned int)pk[0] | ((unsigned int)pk[1] << 16),
          (unsigned int)pk[2] | ((unsigned int)pk[3] << 16)};
    } else if (VEC == 2) {
      *(unsigned int*)((ushort_t*)outp + o) =
          (unsigned int)pk[0] | ((unsigned int)pk[1] << 16);
    } else {
      ((ushort_t*)outp)[o] = pk[0];
    }
  } else {
    size_t o = (size_t)r * D + f0;
#pragma unroll
    for (int q = 0; q < VEC; ++q) ((float*)outp)[o + q] = a[q];
  }
}

// ---------------- launch ----------------
extern "C" void kernel_launch(void* const* d_in, const int* in_sizes, int n_in,
                              void* d_out, int out_size, void* d_ws, size_t ws_size,
                              hipStream_t stream) {
  const void* x     = d_in[0];
  const int*  rows  = (const int*)d_in[1];
  const int*  cols  = (const int*)d_in[2];
  const void* vals  = d_in[3];
  const void* W1    = d_in[4];
  const void* b1    = d_in[5];
  const void* W2    = d_in[6];
  const void* b2    = d_in[7];
  const void* W3    = d_in[8];
  const void* b3    = d_in[9];
  const void* mask1 = d_in[10];
  const void* mask2 = d_in[11];

  const int H1  = in_sizes[5];            // 256
  const int H2  = in_sizes[7];            // 128
  const int OUT = in_sizes[9];            // 64
  const int IN  = in_sizes[4] / H1;       // 256
  const int N   = in_sizes[0] / IN;       // 50000
  const int E   = in_sizes[1];            // 800000
  const int W1n = in_sizes[4], W2n = in_sizes[6], W3n = in_sizes[8];
  const int Np  = ((N + 15) / 16) * 16;   // padded rows for fragment tiles

  char* ws = (char*)d_ws;
  size_t off = 0;
  auto alloc = [&](size_t bytes) -> void* {
    void* p = ws + off;
    off = (off + bytes + 255) & ~(size_t)255;
    return p;
  };
  int*      modes     = (int*)alloc(4 * 4);
  int*      row_start = (int*)alloc((size_t)(N + 1) * 4);
  int*      cnt       = (int*)alloc((size_t)N * 8);   // [cnt | fill]
  int*      part      = (int*)alloc(1024 * 4);
  int2*     ecv       = (int2*)alloc((size_t)E * 8);
  ushort_t* whi       = (ushort_t*)alloc((size_t)(W1n + W2n + W3n) * 2);
  ushort_t* wlo       = (ushort_t*)alloc((size_t)(W1n + W2n + W3n) * 2);
  float*    biasf     = (float*)alloc((size_t)(H1 + H2 + OUT) * 4);
  ushort_t* bufA      = (ushort_t*)alloc((size_t)Np * H1 * 2);   // 25.6 MB (frag)
  ushort_t* bufB      = (ushort_t*)alloc((size_t)Np * H1 * 2);   // 25.6 MB (row-major G)
  ushort_t* bufC      = (ushort_t*)alloc((size_t)Np * H1 * 2);   // 25.6 MB (frag)
  // total ~84 MB (<=110 MB proven safe in r3)

  int* fmode = modes;
  int* mm1   = modes + 1;
  int* mm2   = modes + 2;
  int* fill  = cnt + N;
  ushort_t* w1hi = whi,             *w1lo = wlo;
  ushort_t* w2hi = whi + W1n,       *w2lo = wlo + W1n;
  ushort_t* w3hi = whi + W1n + W2n, *w3lo = wlo + W1n + W2n;

  // prep: sniff (3 blocks) + zero cnt/fill
  prep_kernel<<<259, 256, 0, stream>>>(x, mask1, mask2, modes, cnt, 2 * N);

  // CSR build with parallel scan
  const int P = (N + 255) / 256;
  hist_kernel<<<1024, 256, 0, stream>>>(rows, cnt, E);
  scan_part_kernel<<<P, 256, 0, stream>>>(cnt, part, N);
  scan_top_kernel<<<1, 1024, 0, stream>>>(part, P);
  scan_apply_kernel<<<P, 256, 0, stream>>>(cnt, part, row_start, N);
  scatter_kernel<<<1024, 256, 0, stream>>>(rows, cols, vals, fmode, row_start, fill, ecv, E);

  // single conversion launch: W splits + biases + x->bf16 (ALL fragment order)
  convert_all_kernel<<<2048, 256, 0, stream>>>(
      W1, W2, W3, b1, b2, b3, x, fmode, whi, wlo, biasf, bufA,
      W1n, W2n, W3n, H1, H2, OUT, IN, H1, H2, N * IN);

  const int GEMM_BLOCKS = 1024;            // 4096 waves; % {16,8,4} == 0
  int spmm_grid = (N + 3) / 4;

  // layer 1: GEMM(IN->H1, A=bufA frag) -> bufB row-major -> SpMM -> bufC frag
  gemm_breg_kernel<8><<<GEMM_BLOCKS, 256, 0, stream>>>(
      bufA, w1hi, w1lo, biasf, bufB, H1, N, H1 / 16);
  spmm7_kernel<1, 4><<<spmm_grid, 256, 0, stream>>>(
      row_start, ecv, bufB, H1, mask1, mm1, bufC, N);
  // layer 2: GEMM(H1->H2, A=bufC frag) -> bufB row-major -> SpMM -> bufA frag
  gemm_breg_kernel<8><<<GEMM_BLOCKS, 256, 0, stream>>>(
      bufC, w2hi, w2lo, biasf + H1, bufB, H2, N, H2 / 16);
  spmm7_kernel<1, 2><<<spmm_grid, 256, 0, stream>>>(
      row_start, ecv, bufB, H2, mask2, mm2, bufA, N);
  // layer 3: GEMM(H2->OUT, A=bufA frag) -> bufB row-major -> SpMM -> f32 d_out
  gemm_breg_kernel<4><<<GEMM_BLOCKS, 256, 0, stream>>>(
      bufA, w3hi, w3lo, biasf + H1 + H2, bufB, OUT, N, OUT / 16);
  spmm7_kernel<0, 1><<<spmm_grid, 256, 0, stream>>>(
      row_start, ecv, bufB, OUT, nullptr, fmode, d_out, N);
}

// Round 16
// 439.390 us; speedup vs baseline: 1.6128x; 1.0332x over previous
//
#include <hip/hip_runtime.h>

// ===========================================================================
// ViewGCNEncoder r16 = r15 + (1) LDS-staged frag-order SpMM writes (r15's
// scatter stores cost +9us: 32x16B chunks/wave + partial-line RMW; a 64B
// line = 4 consecutive rows' chunks = exactly one block -> stage in LDS,
// flush full lines), (2) uint4/uint2 mask loads, (3) scatter+convert fused.
// 12 launches. Workspace ~84 MB (<=110 MB proven safe).
// ===========================================================================

typedef unsigned short ushort_t;
typedef __attribute__((ext_vector_type(8))) short bf16x8;   // 8 bf16 = 4 VGPRs
typedef __attribute__((ext_vector_type(4))) float f32x4;
typedef __attribute__((ext_vector_type(2))) unsigned int u32x2;
typedef __attribute__((ext_vector_type(4))) unsigned int u32x4;

__device__ __forceinline__ float bf2f(ushort_t u) {
  return __uint_as_float(((unsigned int)u) << 16);
}
__device__ __forceinline__ ushort_t f2bf(float f) {
  unsigned int u = __float_as_uint(f);
  return (ushort_t)((u + 0x7FFFu + ((u >> 16) & 1u)) >> 16);  // RNE
}
__device__ __forceinline__ float read_f(const void* p, int fm, size_t i) {
  return fm ? bf2f(((const ushort_t*)p)[i]) : ((const float*)p)[i];
}

// fragment-order offset: tile-major 16-row tiles; within tile kc-chunk(32 k)
// then lane-linear (lane = (m&15)+16*((k>>3)&3), 8 elems each).
__device__ __forceinline__ size_t frag_off(int m, int k, int K) {
  return (size_t)(m >> 4) * 16 * K + ((size_t)(k >> 5) << 9) +
         (((k >> 3) & 3) << 7) + ((m & 15) << 3) + (k & 7);
}

__device__ __forceinline__ bool mask_keep(const void* mask, int mm, size_t o) {
  switch (mm) {
    case 1:  return ((const int*)mask)[o] != 0;
    case 2:  return ((const unsigned int*)mask)[o] != 0u;
    case 3:  return ((const ushort_t*)mask)[o] != 0;
    default: return ((const unsigned char*)mask)[o] != 0;
  }
}

// ---------------- prep: dtype sniff (blocks 0-2) + zero cnt/fill (blocks 3+)
__global__ void prep_kernel(const void* __restrict__ x,
                            const void* __restrict__ m1,
                            const void* __restrict__ m2,
                            int* __restrict__ modes,
                            int* __restrict__ zero_region, int zn) {
  if (blockIdx.x == 0) {
    __shared__ int bfok;
    if (threadIdx.x == 0) bfok = 1;
    __syncthreads();
    for (int i = threadIdx.x; i < 8192; i += blockDim.x) {
      ushort_t h = ((const ushort_t*)x)[i];
      int e = (h >> 7) & 0xFF;
      if (!(h == 0 || (e >= 95 && e <= 133))) atomicAnd(&bfok, 0);
    }
    __syncthreads();
    if (threadIdx.x == 0) modes[0] = bfok;   // 1=bf16, 0=f32
  } else if (blockIdx.x <= 2) {
    const void* p = (blockIdx.x == 1) ? m1 : m2;
    __shared__ int ok[4];  // [i32, f32, bf16, u8]
    if (threadIdx.x < 4) ok[threadIdx.x] = 1;
    __syncthreads();
    for (int i = threadIdx.x; i < 4096; i += blockDim.x) {
      unsigned int w = ((const unsigned int*)p)[i];
      if (!(w == 0u || w == 1u)) atomicAnd(&ok[0], 0);
      if (!(w == 0u || w == 0x3F800000u)) atomicAnd(&ok[1], 0);
      unsigned int h16 = w >> 16, l16 = w & 0xFFFFu;
      if (!((h16 == 0u || h16 == 0x3F80u) && (l16 == 0u || l16 == 0x3F80u)))
        atomicAnd(&ok[2], 0);
      if (((w | (w >> 8) | (w >> 16) | (w >> 24)) & 0xFEu) != 0u) atomicAnd(&ok[3], 0);
    }
    __syncthreads();
    if (threadIdx.x == 0)
      modes[blockIdx.x] = ok[0] ? 1 : (ok[1] ? 2 : (ok[2] ? 3 : 0));
  } else {
    int i = (blockIdx.x - 3) * blockDim.x + threadIdx.x;
    int stride = (gridDim.x - 3) * blockDim.x;
    for (; i < zn; i += stride) zero_region[i] = 0;
  }
}

// ---------------- CSR build (frozen) ----------------
__global__ void hist_kernel(const int* __restrict__ rows, int* __restrict__ cnt, int E) {
  int i = blockIdx.x * blockDim.x + threadIdx.x;
  int stride = gridDim.x * blockDim.x;
  for (; i < E; i += stride) atomicAdd(&cnt[rows[i]], 1);
}

__global__ void scan_part_kernel(const int* __restrict__ cnt, int* __restrict__ part, int n) {
  __shared__ int s[256];
  int i = blockIdx.x * 256 + threadIdx.x;
  s[threadIdx.x] = (i < n) ? cnt[i] : 0;
  __syncthreads();
  for (int off = 128; off > 0; off >>= 1) {
    if (threadIdx.x < off) s[threadIdx.x] += s[threadIdx.x + off];
    __syncthreads();
  }
  if (threadIdx.x == 0) part[blockIdx.x] = s[0];
}

__global__ __launch_bounds__(1024) void scan_top_kernel(int* __restrict__ part, int P) {
  __shared__ int s[1024];
  int t = threadIdx.x;
  int v = (t < P) ? part[t] : 0;
  s[t] = v;
  __syncthreads();
  for (int off = 1; off < 1024; off <<= 1) {
    int x = s[t];
    int y = (t >= off) ? s[t - off] : 0;
    __syncthreads();
    s[t] = x + y;
    __syncthreads();
  }
  if (t < P) part[t] = s[t] - v;   // exclusive
}

__global__ void scan_apply_kernel(const int* __restrict__ cnt, const int* __restrict__ part,
                                  int* __restrict__ row_start, int n) {
  __shared__ int s[256];
  int base = part[blockIdx.x];
  int i = blockIdx.x * 256 + threadIdx.x;
  int v = (i < n) ? cnt[i] : 0;
  s[threadIdx.x] = v;
  __syncthreads();
  for (int off = 1; off < 256; off <<= 1) {
    int x = s[threadIdx.x];
    int y = (threadIdx.x >= off) ? s[threadIdx.x - off] : 0;
    __syncthreads();
    s[threadIdx.x] = x + y;
    __syncthreads();
  }
  if (i < n) row_start[i] = base + s[threadIdx.x] - v;
  if (i == n - 1) row_start[n] = base + s[threadIdx.x];
}

// ---------------- fused scatter (blocks 0..1023) + convert (blocks 1024+) ---
__global__ void scatter_convert_kernel(
    const int* __restrict__ rows, const int* __restrict__ cols,
    const void* __restrict__ vals, const int* __restrict__ fm_p,
    const int* __restrict__ row_start, int* __restrict__ fill,
    int2* __restrict__ ecv, int E,
    const void* __restrict__ W1, const void* __restrict__ W2, const void* __restrict__ W3,
    const void* __restrict__ b1, const void* __restrict__ b2, const void* __restrict__ b3,
    const void* __restrict__ x,
    ushort_t* __restrict__ whi, ushort_t* __restrict__ wlo,
    float* __restrict__ biasf, ushort_t* __restrict__ xbf,
    int n1, int n2, int n3, int h1, int h2, int h3, int K1, int K2, int K3, int nx) {
  int fm = *fm_p;
  if (blockIdx.x < 1024) {
    // --- scatter: packed (col, val) edge stream ---
    int i = blockIdx.x * blockDim.x + threadIdx.x;
    int stride = 1024 * blockDim.x;
    for (; i < E; i += stride) {
      int r = rows[i];
      int pos = atomicAdd(&fill[r], 1);
      int idx = row_start[r] + pos;
      ecv[idx] = make_int2(cols[i], __float_as_int(read_f(vals, fm, i)));
    }
  } else {
    // --- convert: W split + bias + x->bf16, all fragment order ---
    int wtot = n1 + n2 + n3;
    int btot = h1 + h2 + h3;
    int nx4 = nx / 4;
    int total = wtot + btot + nx4;
    int i = (blockIdx.x - 1024) * blockDim.x + threadIdx.x;
    int stride = (gridDim.x - 1024) * blockDim.x;
    for (; i < total; i += stride) {
      if (i < wtot) {
        const void* src; int j, K; size_t base;
        if (i < n1) { src = W1; j = i; K = K1; base = 0; }
        else if (i < n1 + n2) { src = W2; j = i - n1; K = K2; base = n1; }
        else { src = W3; j = i - n1 - n2; K = K3; base = (size_t)n1 + n2; }
        int n = j / K, k = j - n * K;
        float v = read_f(src, fm, j);
        ushort_t h = f2bf(v);
        size_t o = base + frag_off(n, k, K);
        whi[o] = h;
        wlo[o] = f2bf(v - bf2f(h));
      } else if (i < wtot + btot) {
        int k = i - wtot;
        const void* src; int j;
        if (k < h1) { src = b1; j = k; }
        else if (k < h1 + h2) { src = b2; j = k - h1; }
        else { src = b3; j = k - h1 - h2; }
        biasf[k] = read_f(src, fm, j);
      } else {
        int k4 = i - wtot - btot;          // 4 consecutive elems of x
        int m = k4 / (K1 / 4);
        int k0 = (k4 - m * (K1 / 4)) * 4;
        ushort_t p0, p1, p2, p3;
        if (fm == 0) {
          f32x4 v = ((const f32x4*)x)[k4];
          p0 = f2bf(v[0]); p1 = f2bf(v[1]); p2 = f2bf(v[2]); p3 = f2bf(v[3]);
        } else {
          const ushort_t* xb = (const ushort_t*)x + (size_t)k4 * 4;
          p0 = xb[0]; p1 = xb[1]; p2 = xb[2]; p3 = xb[3];
        }
        size_t o = frag_off(m, k0, K1);
        *(u32x2*)(xbf + o) = (u32x2){
            (unsigned int)p0 | ((unsigned int)p1 << 16),
            (unsigned int)p2 | ((unsigned int)p3 << 16)};
      }
    }
  }
}

// ---------------- GEMM: fragment-ordered A and W (frozen r15) ---------------
template<int KC>
__global__ __launch_bounds__(256) void gemm_breg_kernel(
    const ushort_t* __restrict__ A,
    const ushort_t* __restrict__ Whi, const ushort_t* __restrict__ Wlo,
    const float* __restrict__ bias, ushort_t* __restrict__ g, int ldg,
    int M, int nct) {
  const int K = KC * 32;
  int wave = threadIdx.x >> 6, lane = threadIdx.x & 63;
  int gw = blockIdx.x * 4 + wave;
  int NW = gridDim.x * 4;
  int mr = lane & 15, quad = lane >> 4;
  int ct = gw % nct;
  int nrt = (M + 15) >> 4;
  int ntasks = nct * nrt;
  if (gw >= ntasks) return;

  bf16x8 wh[KC], wl[KC];
  {
    const ushort_t* wp = Whi + (size_t)ct * 16 * K + lane * 8;
    const ushort_t* wq = Wlo + (size_t)ct * 16 * K + lane * 8;
#pragma unroll
    for (int kc = 0; kc < KC; ++kc) {
      wh[kc] = *(const bf16x8*)(wp + kc * 512);
      wl[kc] = *(const bf16x8*)(wq + kc * 512);
    }
  }
  int col = ct * 16 + mr;
  float bv = bias[col];

  int task = gw;
  bf16x8 af[KC];
  {
    const ushort_t* ap = A + (size_t)(task / nct) * 16 * K + lane * 8;
#pragma unroll
    for (int kc = 0; kc < KC; ++kc) af[kc] = *(const bf16x8*)(ap + kc * 512);
  }

#pragma unroll 1
  for (;;) {
    int next = task + NW;
    bool has_next = next < ntasks;
    bf16x8 afn[KC];
    if (has_next) {
      const ushort_t* ap = A + (size_t)(next / nct) * 16 * K + lane * 8;
#pragma unroll
      for (int kc = 0; kc < KC; ++kc) afn[kc] = *(const bf16x8*)(ap + kc * 512);
    }

    f32x4 acc[4];
#pragma unroll
    for (int t = 0; t < 4; ++t) acc[t] = (f32x4){0.f, 0.f, 0.f, 0.f};
#pragma unroll
    for (int kc = 0; kc < KC; ++kc) {
      acc[(2 * kc) & 3] = __builtin_amdgcn_mfma_f32_16x16x32_bf16(af[kc], wh[kc], acc[(2 * kc) & 3], 0, 0, 0);
      acc[(2 * kc + 1) & 3] = __builtin_amdgcn_mfma_f32_16x16x32_bf16(af[kc], wl[kc], acc[(2 * kc + 1) & 3], 0, 0, 0);
    }
    int m0 = (task / nct) * 16;
#pragma unroll
    for (int r = 0; r < 4; ++r) {
      int row = m0 + quad * 4 + r;
      float s = ((acc[0][r] + acc[1][r]) + (acc[2][r] + acc[3][r])) + bv;
      if (row < M) g[(size_t)row * ldg + col] = f2bf(s);
    }
    if (!has_next) break;
#pragma unroll
    for (int kc = 0; kc < KC; ++kc) af[kc] = afn[kc];
    task = next;
  }
}

// ---------------- SpMM v8: gathers (r14) + LDS-staged frag flush ------------
// out[r,f] = sum_e val[e]*G[col[e],f].  One wave per row, VEC elems/lane.
// MODE 1: leaky+mask (uint4/uint2 vector mask load) -> LDS stage ->
//         coalesced 64B-line frag-order flush (4 rows/block = full lines).
// MODE 0: plain -> f32 row-major (final d_out).
template<int MODE, int VEC>
__global__ __launch_bounds__(256) void spmm8_kernel(
    const int* __restrict__ row_start, const int2* __restrict__ ecv,
    const ushort_t* __restrict__ G, int D,
    const void* __restrict__ mask, const int* __restrict__ mmode_p,
    void* __restrict__ outp, int N) {
  __shared__ ushort_t stage[1024];         // 4 rows x up to 256 cols
  int wave = threadIdx.x >> 6, lane = threadIdx.x & 63;
  int r = blockIdx.x * 4 + wave;
  bool active = r < N;
  float a[VEC];
#pragma unroll
  for (int q = 0; q < VEC; ++q) a[q] = 0.f;
  int f0 = lane * VEC;

  if (active) {
    int e  = __builtin_amdgcn_readfirstlane(row_start[r]);
    int e1 = __builtin_amdgcn_readfirstlane(row_start[r + 1]);
    for (; e + 8 <= e1; e += 8) {
      int2 cv[8];
#pragma unroll
      for (int j = 0; j < 8; ++j) cv[j] = ecv[e + j];
      if (VEC == 4) {
        u32x2 gg[8];
#pragma unroll
        for (int j = 0; j < 8; ++j)
          gg[j] = *(const u32x2*)(G + (size_t)cv[j].x * D + f0);
#pragma unroll
        for (int j = 0; j < 8; ++j) {
          float v = __int_as_float(cv[j].y);
          a[0] += v * bf2f((ushort_t)gg[j][0]);
          a[1] += v * bf2f((ushort_t)(gg[j][0] >> 16));
          a[2] += v * bf2f((ushort_t)gg[j][1]);
          a[3] += v * bf2f((ushort_t)(gg[j][1] >> 16));
        }
      } else if (VEC == 2) {
        unsigned int gg[8];
#pragma unroll
        for (int j = 0; j < 8; ++j)
          gg[j] = *(const unsigned int*)(G + (size_t)cv[j].x * D + f0);
#pragma unroll
        for (int j = 0; j < 8; ++j) {
          float v = __int_as_float(cv[j].y);
          a[0] += v * bf2f((ushort_t)gg[j]);
          a[1] += v * bf2f((ushort_t)(gg[j] >> 16));
        }
      } else {
        ushort_t h[8];
#pragma unroll
        for (int j = 0; j < 8; ++j) h[j] = G[(size_t)cv[j].x * D + f0];
#pragma unroll
        for (int j = 0; j < 8; ++j) a[0] += __int_as_float(cv[j].y) * bf2f(h[j]);
      }
    }
    if (e < e1) {
      int idx[8]; float v[8];
#pragma unroll
      for (int j = 0; j < 8; ++j) {
        int ee = e + j;
        bool ok = ee < e1;
        int2 cv = ecv[ok ? ee : e1 - 1];
        idx[j] = cv.x;
        v[j] = ok ? __int_as_float(cv.y) : 0.f;
      }
      if (VEC == 4) {
        u32x2 gg[8];
#pragma unroll
        for (int j = 0; j < 8; ++j)
          gg[j] = *(const u32x2*)(G + (size_t)idx[j] * D + f0);
#pragma unroll
        for (int j = 0; j < 8; ++j) {
          a[0] += v[j] * bf2f((ushort_t)gg[j][0]);
          a[1] += v[j] * bf2f((ushort_t)(gg[j][0] >> 16));
          a[2] += v[j] * bf2f((ushort_t)gg[j][1]);
          a[3] += v[j] * bf2f((ushort_t)(gg[j][1] >> 16));
        }
      } else if (VEC == 2) {
        unsigned int gg[8];
#pragma unroll
        for (int j = 0; j < 8; ++j)
          gg[j] = *(const unsigned int*)(G + (size_t)idx[j] * D + f0);
#pragma unroll
        for (int j = 0; j < 8; ++j) {
          a[0] += v[j] * bf2f((ushort_t)gg[j]);
          a[1] += v[j] * bf2f((ushort_t)(gg[j] >> 16));
        }
      } else {
        ushort_t h[8];
#pragma unroll
        for (int j = 0; j < 8; ++j) h[j] = G[(size_t)idx[j] * D + f0];
#pragma unroll
        for (int j = 0; j < 8; ++j) a[0] += v[j] * bf2f(h[j]);
      }
    }
  }

  if (MODE == 1) {
    if (active) {
      size_t om = (size_t)r * D + f0;      // mask is row-major
      int mm = *mmode_p;
      bool keep[VEC];
      if (mm == 1 || mm == 2) {            // 4B/elem int-or-f32bits: vector load
        if (VEC == 4) {
          u32x4 mv = *(const u32x4*)((const unsigned int*)mask + om);
#pragma unroll
          for (int q = 0; q < VEC; ++q) keep[q] = mv[q] != 0u;
        } else if (VEC == 2) {
          u32x2 mv = *(const u32x2*)((const unsigned int*)mask + om);
#pragma unroll
          for (int q = 0; q < VEC; ++q) keep[q] = mv[q] != 0u;
        } else {
          keep[0] = ((const unsigned int*)mask)[om] != 0u;
        }
      } else {
#pragma unroll
        for (int q = 0; q < VEC; ++q) keep[q] = mask_keep(mask, mm, om + q);
      }
#pragma unroll
      for (int q = 0; q < VEC; ++q) {
        float t = a[q];
        t = (t >= 0.f) ? t : 0.2f * t;             // leaky relu 0.2
        t = keep[q] ? t * 1.25f : 0.f;             // keep = 1/(1-0.2)
        stage[wave * D + f0 + q] = f2bf(t);
      }
    }
    __syncthreads();
    // flush: D threads, one 8B (4-elem) piece each; 64B line = 4 rows' chunks
    if (threadIdx.x < D) {
      int g = threadIdx.x >> 3, s = threadIdx.x & 7;   // group, sub
      int kc = g >> 2, quad = g & 3;
      int sr = s >> 1;                                  // source row in block
      int r0 = blockIdx.x * 4;
      if (r0 + sr < N) {
        int kk = kc * 32 + quad * 8 + (s & 1) * 4;
        size_t dst = (size_t)(r0 >> 4) * 16 * D + ((size_t)kc << 9) +
                     (quad << 7) + ((r0 & 15) << 3) + s * 4;
        *(u32x2*)((ushort_t*)outp + dst) = *(const u32x2*)(stage + sr * D + kk);
      }
    }
  } else {
    if (active) {
      size_t o = (size_t)r * D + f0;
#pragma unroll
      for (int q = 0; q < VEC; ++q) ((float*)outp)[o + q] = a[q];
    }
  }
}

// ---------------- launch ----------------
extern "C" void kernel_launch(void* const* d_in, const int* in_sizes, int n_in,
                              void* d_out, int out_size, void* d_ws, size_t ws_size,
                              hipStream_t stream) {
  const void* x     = d_in[0];
  const int*  rows  = (const int*)d_in[1];
  const int*  cols  = (const int*)d_in[2];
  const void* vals  = d_in[3];
  const void* W1    = d_in[4];
  const void* b1    = d_in[5];
  const void* W2    = d_in[6];
  const void* b2    = d_in[7];
  const void* W3    = d_in[8];
  const void* b3    = d_in[9];
  const void* mask1 = d_in[10];
  const void* mask2 = d_in[11];

  const int H1  = in_sizes[5];            // 256
  const int H2  = in_sizes[7];            // 128
  const int OUT = in_sizes[9];            // 64
  const int IN  = in_sizes[4] / H1;       // 256
  const int N   = in_sizes[0] / IN;       // 50000
  const int E   = in_sizes[1];            // 800000
  const int W1n = in_sizes[4], W2n = in_sizes[6], W3n = in_sizes[8];
  const int Np  = ((N + 15) / 16) * 16;

  char* ws = (char*)d_ws;
  size_t off = 0;
  auto alloc = [&](size_t bytes) -> void* {
    void* p = ws + off;
    off = (off + bytes + 255) & ~(size_t)255;
    return p;
  };
  int*      modes     = (int*)alloc(4 * 4);
  int*      row_start = (int*)alloc((size_t)(N + 1) * 4);
  int*      cnt       = (int*)alloc((size_t)N * 8);   // [cnt | fill]
  int*      part      = (int*)alloc(1024 * 4);
  int2*     ecv       = (int2*)alloc((size_t)E * 8);
  ushort_t* whi       = (ushort_t*)alloc((size_t)(W1n + W2n + W3n) * 2);
  ushort_t* wlo       = (ushort_t*)alloc((size_t)(W1n + W2n + W3n) * 2);
  float*    biasf     = (float*)alloc((size_t)(H1 + H2 + OUT) * 4);
  ushort_t* bufA      = (ushort_t*)alloc((size_t)Np * H1 * 2);   // frag
  ushort_t* bufB      = (ushort_t*)alloc((size_t)Np * H1 * 2);   // row-major G
  ushort_t* bufC      = (ushort_t*)alloc((size_t)Np * H1 * 2);   // frag
  // total ~84 MB (<=110 MB proven safe in r3)

  int* fmode = modes;
  int* mm1   = modes + 1;
  int* mm2   = modes + 2;
  int* fill  = cnt + N;
  ushort_t* w1hi = whi,             *w1lo = wlo;
  ushort_t* w2hi = whi + W1n,       *w2lo = wlo + W1n;
  ushort_t* w3hi = whi + W1n + W2n, *w3lo = wlo + W1n + W2n;

  // prep: sniff (3 blocks) + zero cnt/fill
  prep_kernel<<<259, 256, 0, stream>>>(x, mask1, mask2, modes, cnt, 2 * N);

  // CSR build with parallel scan
  const int P = (N + 255) / 256;
  hist_kernel<<<1024, 256, 0, stream>>>(rows, cnt, E);
  scan_part_kernel<<<P, 256, 0, stream>>>(cnt, part, N);
  scan_top_kernel<<<1, 1024, 0, stream>>>(part, P);
  scan_apply_kernel<<<P, 256, 0, stream>>>(cnt, part, row_start, N);

  // fused: scatter (1024 blocks) + conversions (2048 blocks)
  scatter_convert_kernel<<<3072, 256, 0, stream>>>(
      rows, cols, vals, fmode, row_start, fill, ecv, E,
      W1, W2, W3, b1, b2, b3, x, whi, wlo, biasf, bufA,
      W1n, W2n, W3n, H1, H2, OUT, IN, H1, H2, N * IN);

  const int GEMM_BLOCKS = 1024;            // 4096 waves; % {16,8,4} == 0
  int spmm_grid = (N + 3) / 4;

  // layer 1: GEMM(IN->H1, A=bufA frag) -> bufB row-major -> SpMM -> bufC frag
  gemm_breg_kernel<8><<<GEMM_BLOCKS, 256, 0, stream>>>(
      bufA, w1hi, w1lo, biasf, bufB, H1, N, H1 / 16);
  spmm8_kernel<1, 4><<<spmm_grid, 256, 0, stream>>>(
      row_start, ecv, bufB, H1, mask1, mm1, bufC, N);
  // layer 2: GEMM(H1->H2, A=bufC frag) -> bufB row-major -> SpMM -> bufA frag
  gemm_breg_kernel<8><<<GEMM_BLOCKS, 256, 0, stream>>>(
      bufC, w2hi, w2lo, biasf + H1, bufB, H2, N, H2 / 16);
  spmm8_kernel<1, 2><<<spmm_grid, 256, 0, stream>>>(
      row_start, ecv, bufB, H2, mask2, mm2, bufA, N);
  // layer 3: GEMM(H2->OUT, A=bufA frag) -> bufB row-major -> SpMM -> f32 d_out
  gemm_breg_kernel<4><<<GEMM_BLOCKS, 256, 0, stream>>>(
      bufA, w3hi, w3lo, biasf + H1 + H2, bufB, OUT, N, OUT / 16);
  spmm8_kernel<0, 1><<<spmm_grid, 256, 0, stream>>>(
      row_start, ecv, bufB, OUT, nullptr, fmode, d_out, N);
}